// Round 3
// baseline (1764.234 us; speedup 1.0000x reference)
//
#include <hip/hip_runtime.h>
#include <math.h>

#define BATCH   64
#define SEQLEN  128
#define EMBED   512
#define HID     1024
#define NSTEP   127
#define OUT0    65
#define NOUT    62
#define R_GX    4          // gx ring depth (slots of one timestep each)

typedef unsigned short ushort_t;
typedef unsigned long long ull_t;
typedef __attribute__((ext_vector_type(8))) __bf16 bf16x8;
typedef __attribute__((ext_vector_type(4))) float  f32x4;
typedef __attribute__((ext_vector_type(2))) float  f32x2;

__device__ __forceinline__ float sigmoidf_(float x) { return 1.f / (1.f + expf(-x)); }

__device__ __forceinline__ ushort_t f2bf(float f) {
    unsigned u = __builtin_bit_cast(unsigned, f);
    unsigned r = (u + 0x7FFFu + ((u >> 16) & 1u)) >> 16;   // round-to-nearest-even
    return (ushort_t)r;
}
__device__ __forceinline__ float bf2f(ushort_t s) {
    unsigned u = ((unsigned)s) << 16;
    return __builtin_bit_cast(float, u);
}

// split 8 consecutive floats into bf16-hi / bf16-lo fragments
__device__ __forceinline__ void split8(const float* __restrict__ src, bf16x8& hv, bf16x8& lv) {
    float4 f0 = *(const float4*)src;
    float4 f1 = *(const float4*)(src + 4);
    float fv[8] = { f0.x, f0.y, f0.z, f0.w, f1.x, f1.y, f1.z, f1.w };
    #pragma unroll
    for (int i = 0; i < 8; ++i) {
        ushort_t hs = f2bf(fv[i]);
        ushort_t ls = f2bf(fv[i] - bf2f(hs));
        hv[i] = __builtin_bit_cast(__bf16, hs);
        lv[i] = __builtin_bit_cast(__bf16, ls);
    }
}

// 12 MFMAs: bf16x3 scheme (ah*bh + al*bh + ah*bl) for 2 M-tiles x 2 N-tiles
__device__ __forceinline__ void mfma12(
    bf16x8 ah0, bf16x8 al0, bf16x8 ah1, bf16x8 al1,
    bf16x8 bh0, bf16x8 bl0, bf16x8 bh1, bf16x8 bl1,
    f32x4 (&acc)[2][2])
{
    acc[0][0] = __builtin_amdgcn_mfma_f32_16x16x32_bf16(ah0, bh0, acc[0][0], 0, 0, 0);
    acc[0][1] = __builtin_amdgcn_mfma_f32_16x16x32_bf16(ah0, bh1, acc[0][1], 0, 0, 0);
    acc[1][0] = __builtin_amdgcn_mfma_f32_16x16x32_bf16(ah1, bh0, acc[1][0], 0, 0, 0);
    acc[1][1] = __builtin_amdgcn_mfma_f32_16x16x32_bf16(ah1, bh1, acc[1][1], 0, 0, 0);
    acc[0][0] = __builtin_amdgcn_mfma_f32_16x16x32_bf16(al0, bh0, acc[0][0], 0, 0, 0);
    acc[0][1] = __builtin_amdgcn_mfma_f32_16x16x32_bf16(al0, bh1, acc[0][1], 0, 0, 0);
    acc[1][0] = __builtin_amdgcn_mfma_f32_16x16x32_bf16(al1, bh0, acc[1][0], 0, 0, 0);
    acc[1][1] = __builtin_amdgcn_mfma_f32_16x16x32_bf16(al1, bh1, acc[1][1], 0, 0, 0);
    acc[0][0] = __builtin_amdgcn_mfma_f32_16x16x32_bf16(ah0, bl0, acc[0][0], 0, 0, 0);
    acc[0][1] = __builtin_amdgcn_mfma_f32_16x16x32_bf16(ah0, bl1, acc[0][1], 0, 0, 0);
    acc[1][0] = __builtin_amdgcn_mfma_f32_16x16x32_bf16(ah1, bl0, acc[1][0], 0, 0, 0);
    acc[1][1] = __builtin_amdgcn_mfma_f32_16x16x32_bf16(ah1, bl1, acc[1][1], 0, 0, 0);
}

// ===================== MFMA path prep (unchanged layouts) =====================

__global__ __launch_bounds__(256) void init_mfma(
    const float* __restrict__ h0, const float* __restrict__ c0,
    float* __restrict__ cT, ushort_t* __restrict__ hf_hi, ushort_t* __restrict__ hf_lo)
{
    int id = blockIdx.x * 256 + threadIdx.x;   // u*64+b
    int u = id >> 6, b = id & 63;
    cT[id] = c0[b * HID + u];
    float h = h0[b * HID + u];
    ushort_t hs = f2bf(h);
    ushort_t ls = f2bf(h - bf2f(hs));
    size_t idx = (((size_t)(u >> 5)) * 4 + (b >> 4)) * 512
               + ((((u & 31) >> 3) * 16) + (b & 15)) * 8 + (u & 7);
    hf_hi[idx] = hs;
    hf_lo[idx] = ls;
}

__global__ __launch_bounds__(256) void embed_frag(
    const int* __restrict__ prob, const float* __restrict__ embed,
    ushort_t* __restrict__ xf_hi, ushort_t* __restrict__ xf_lo)
{
    int t = blockIdx.x;
    for (int e = threadIdx.x; e < 4096; e += 256) {
        int b  = e >> 6;         // 0..63
        int kb = e & 63;         // k-block of 8
        int k  = kb * 8;
        int tok = prob[b * SEQLEN + t];
        const float* row = embed + (size_t)tok * EMBED + k;
        bf16x8 hv, lv;
        split8(row, hv, lv);
        size_t idx = (((size_t)t * 16 + (kb >> 2)) * 4 + (b >> 4)) * 512
                   + (((kb & 3) * 16) + (b & 15)) * 8;
        *(bf16x8*)(xf_hi + idx) = hv;
        *(bf16x8*)(xf_lo + idx) = lv;
    }
}

// ===================== fused producer/consumer persistent kernel =====================
// 256 blocks x 512 thr (8 waves: wn = w&1 (N-half), kq = w>>1 (K-quarter)).
// r2 change vs measured r1: A-fragments moved from REGISTERS (which spilled:
// VGPR_Count=128, ~440MB scratch writes, 2x step-time) back to the PROVEN LDS
// image pattern. Consumer A = W_hh 32 rows x K=1024 hi+lo = 128 KB; producer
// A = W_ih 32 rows x K=512 hi+lo = 32 KB (same region). Dynamic LDS 152 KB.
// Everything else (per-quarter h signaling, gx ring, layouts) unchanged from
// the PASSED r1 run.

// K-reduce across the 4 K-quarter waves (per N-half), via 24 KB LDS scratch.
#define KREDUCE() \
    if (kq >= 2) { _Pragma("unroll") for (int a = 0; a < 4; ++a) \
        *(f32x4*)&redf[(((wn * 2 + (kq - 2)) * 4 + a) * 64 + L) * 4] = acc[a >> 1][a & 1]; } \
    __syncthreads(); \
    if (kq < 2) { _Pragma("unroll") for (int a = 0; a < 4; ++a) \
        acc[a >> 1][a & 1] += *(const f32x4*)&redf[(((wn * 2 + kq) * 4 + a) * 64 + L) * 4]; } \
    if (kq == 1) { _Pragma("unroll") for (int a = 0; a < 4; ++a) \
        *(f32x4*)&redf[4096 + ((wn * 4 + a) * 64 + L) * 4] = acc[a >> 1][a & 1]; } \
    __syncthreads(); \
    if (kq == 0) { _Pragma("unroll") for (int a = 0; a < 4; ++a) \
        acc[a >> 1][a & 1] += *(const f32x4*)&redf[4096 + ((wn * 4 + a) * 64 + L) * 4]; }

__global__ __launch_bounds__(512, 2) void lstm_fused(
    const ushort_t* __restrict__ xf_hi, const ushort_t* __restrict__ xf_lo,
    ushort_t* __restrict__ hf_hi, ushort_t* __restrict__ hf_lo,
    const float* __restrict__ cT,
    const float* __restrict__ w_ih, const float* __restrict__ w_hh,
    const float* __restrict__ b_ih, const float* __restrict__ b_hh,
    const float* __restrict__ w_ans, float* __restrict__ pout,
    float* __restrict__ gx, int* __restrict__ bar)
{
    extern __shared__ char smem[];
    ushort_t* a_hi = (ushort_t*)smem;                 // 64 KB (cons: 32 ksteps x 2 mt x 512)
    ushort_t* a_lo = (ushort_t*)(smem + 65536);       // 64 KB
    float*    redf = (float*)   (smem + 131072);      // 24 KB reduce scratch

    const int tid = threadIdx.x;
    const int bid = blockIdx.x;
    const int w   = tid >> 6;            // 0..7
    const int wn  = w & 1;               // N-half (2 N-tiles of 16)
    const int kq  = w >> 1;              // K-quarter 0..3
    const int L   = tid & 63;
    const int n   = L & 15;
    const int q   = L >> 4;

    // bar[qtr*16]: consumer arrival counter per unit-quarter (one line each)
    // bar[256 + p*16]: producer p progress (64 B apart, no false sharing)

    if (bid < 128) {
        // ========================= CONSUMER =========================
        const int u0 = bid * 8;

        // one-time: W_hh -> LDS A-frag image (hi/lo), all 512 threads
        for (int m16 = 0; m16 < 32; ++m16) {
            int mt = m16 >> 4, r = m16 & 15;
            int unit = r >> 2, gate = r & 3;
            const float* wrow = w_hh + ((size_t)gate * HID + u0 + mt * 4 + unit) * HID;
            #pragma unroll
            for (int kk = 0; kk < 2; ++kk) {
                int k = tid + kk * 512;
                float f = wrow[k];
                ushort_t hs = f2bf(f);
                ushort_t ls = f2bf(f - bf2f(hs));
                int off = (((k >> 5) * 2 + mt) << 9)
                        + ((((k & 31) >> 3) * 16 + r) << 3) + (k & 7);
                a_hi[off] = hs;
                a_lo[off] = ls;
            }
        }

        // per-lane state (meaningful for kq==0 waves; harmless elsewhere)
        float c[2][2], bs[2][4], wans[2];
        #pragma unroll
        for (int mt = 0; mt < 2; ++mt) {
            int ug = u0 + mt * 4 + q;
            #pragma unroll
            for (int ntl = 0; ntl < 2; ++ntl)
                c[mt][ntl] = cT[(size_t)ug * 64 + wn * 32 + ntl * 16 + n];
            #pragma unroll
            for (int j = 0; j < 4; ++j)
                bs[mt][j] = b_ih[j * HID + ug] + b_hh[j * HID + ug];
            wans[mt] = w_ans[ug];
        }
        __syncthreads();

        int  lastSeen = 0;
        int* prog_me  = bar + 256 + bid * 16;
        int* gc_me    = bar + kq * 16;

        for (int t = 0; t < NSTEP; ++t) {
            // gx readiness (rare after warmup: producer runs several steps ahead)
            if (kq == 0 && lastSeen < t + 1) {
                int v;
                while ((v = __hip_atomic_load(prog_me, __ATOMIC_RELAXED,
                                              __HIP_MEMORY_SCOPE_AGENT)) < t + 1)
                    __builtin_amdgcn_s_sleep(2);
                lastSeen = v;
                __builtin_amdgcn_fence(__ATOMIC_ACQUIRE, "workgroup");
            }

            // ---- gx partial loads (issued early; latency hides under h-phase) ----
            f32x4 gxr[2][2];
            if (kq == 0) {
                const size_t gb = ((size_t)(t & (R_GX - 1)) * 128 + bid) * 8;
                #pragma unroll
                for (int mt = 0; mt < 2; ++mt)
                    #pragma unroll
                    for (int ntl = 0; ntl < 2; ++ntl) {
                        size_t off = ((gb + mt * 4 + q) * 64 + wn * 32 + ntl * 16 + n) * 4;
                        #pragma unroll
                        for (int jj = 0; jj < 2; ++jj) {
                            ull_t u = __hip_atomic_load(
                                (const ull_t*)(gx + off) + jj,
                                __ATOMIC_RELAXED, __HIP_MEMORY_SCOPE_AGENT);
                            f32x2 f2 = __builtin_bit_cast(f32x2, u);
                            gxr[mt][ntl][jj * 2]     = f2[0];
                            gxr[mt][ntl][jj * 2 + 1] = f2[1];
                        }
                    }
            }

            // wait for this K-quarter of h(t)
            if (t > 0) {
                while (__hip_atomic_load(gc_me, __ATOMIC_RELAXED,
                                         __HIP_MEMORY_SCOPE_AGENT) < 32 * t)
                    __builtin_amdgcn_s_sleep(1);
                __builtin_amdgcn_fence(__ATOMIC_ACQUIRE, "workgroup");
            }

            f32x4 acc[2][2];
            #pragma unroll
            for (int a = 0; a < 4; ++a) acc[a >> 1][a & 1] = (f32x4){0.f, 0.f, 0.f, 0.f};

            // ---- h phase: 8 ksteps, A from LDS, B 2-deep global pipeline ----
            {
                const ushort_t* hb = hf_hi + (((size_t)t * 32 + kq * 8) * 4 + wn * 2) * 512 + L * 8;
                const ushort_t* lb = hf_lo + (((size_t)t * 32 + kq * 8) * 4 + wn * 2) * 512 + L * 8;
                bf16x8 Bh[2][2], Bl[2][2];
                Bh[0][0] = *(const bf16x8*)(hb);        Bl[0][0] = *(const bf16x8*)(lb);
                Bh[0][1] = *(const bf16x8*)(hb + 512);  Bl[0][1] = *(const bf16x8*)(lb + 512);
                #pragma unroll
                for (int ks = 0; ks < 8; ++ks) {
                    const int cur = ks & 1, nxt = cur ^ 1;
                    if (ks < 7) {
                        const size_t o_ = (size_t)(ks + 1) * 2048;
                        Bh[nxt][0] = *(const bf16x8*)(hb + o_);
                        Bl[nxt][0] = *(const bf16x8*)(lb + o_);
                        Bh[nxt][1] = *(const bf16x8*)(hb + o_ + 512);
                        Bl[nxt][1] = *(const bf16x8*)(lb + o_ + 512);
                    }
                    const int ab = (((kq * 8 + ks) * 2) << 9) + (L << 3);
                    bf16x8 ah0 = *(const bf16x8*)(a_hi + ab);
                    bf16x8 al0 = *(const bf16x8*)(a_lo + ab);
                    bf16x8 ah1 = *(const bf16x8*)(a_hi + ab + 512);
                    bf16x8 al1 = *(const bf16x8*)(a_lo + ab + 512);
                    mfma12(ah0, al0, ah1, al1,
                           Bh[cur][0], Bl[cur][0], Bh[cur][1], Bl[cur][1], acc);
                }
            }

            KREDUCE()

            if (kq == 0) {
                // ---- finalize: lane owns units {u0+q, u0+4+q} x batches {wn*32+n, wn*32+16+n} ----
                float pl0 = 0.f, pl1 = 0.f;
                #pragma unroll
                for (int mt = 0; mt < 2; ++mt)
                    #pragma unroll
                    for (int ntl = 0; ntl < 2; ++ntl) {
                        f32x4 g = acc[mt][ntl];
                        float ig = sigmoidf_(g[0] + gxr[mt][ntl][0] + bs[mt][0]);
                        float fg = sigmoidf_(g[1] + gxr[mt][ntl][1] + bs[mt][1]);
                        float gg = tanhf    (g[2] + gxr[mt][ntl][2] + bs[mt][2]);
                        float og = sigmoidf_(g[3] + gxr[mt][ntl][3] + bs[mt][3]);
                        float cn = fg * c[mt][ntl] + ig * gg;
                        c[mt][ntl] = cn;
                        float hn = og * tanhf(cn);

                        int ug = u0 + mt * 4 + q;
                        int bg = wn * 32 + ntl * 16 + n;
                        ushort_t hs = f2bf(hn);
                        ushort_t ls = f2bf(hn - bf2f(hs));
                        size_t idx = (((size_t)(t + 1) * 32 + (ug >> 5)) * 4 + (bg >> 4)) * 512
                                   + ((((ug & 31) >> 3) * 16) + (bg & 15)) * 8 + (ug & 7);
                        __hip_atomic_store(&hf_hi[idx], hs, __ATOMIC_RELAXED,
                                           __HIP_MEMORY_SCOPE_AGENT);
                        __hip_atomic_store(&hf_lo[idx], ls, __ATOMIC_RELAXED,
                                           __HIP_MEMORY_SCOPE_AGENT);
                        float pv = hn * wans[mt];
                        if (ntl == 0) pl0 += pv; else pl1 += pv;
                    }
                pl0 += __shfl_xor(pl0, 16, 64); pl0 += __shfl_xor(pl0, 32, 64);
                pl1 += __shfl_xor(pl1, 16, 64); pl1 += __shfl_xor(pl1, 32, 64);
                if (t >= OUT0 && q == 0) {
                    pout[((size_t)(t - OUT0) * 128 + bid) * 64 + wn * 32 + n]      = pl0;
                    pout[((size_t)(t - OUT0) * 128 + bid) * 64 + wn * 32 + 16 + n] = pl1;
                }
            }

            if (t == NSTEP - 1) break;
            __syncthreads();   // drains hf stores (vmcnt 0) before arrive
            if (tid == 0)
                __hip_atomic_fetch_add(bar + (bid >> 5) * 16, 1, __ATOMIC_RELAXED,
                                       __HIP_MEMORY_SCOPE_AGENT);
        }
    } else {
        // ========================= PRODUCER =========================
        const int p   = bid - 128;
        const int u0p = p * 8;

        // one-time: W_ih -> LDS A-frag image (hi/lo), 16 ksteps x 2 mt
        for (int m16 = 0; m16 < 32; ++m16) {
            int mt = m16 >> 4, r = m16 & 15;
            int unit = r >> 2, gate = r & 3;
            const float* wrow = w_ih + ((size_t)gate * HID + u0p + mt * 4 + unit) * EMBED;
            int k = tid;   // 0..511 covers EMBED
            float f = wrow[k];
            ushort_t hs = f2bf(f);
            ushort_t ls = f2bf(f - bf2f(hs));
            int off = (((k >> 5) * 2 + mt) << 9)
                    + ((((k & 31) >> 3) * 16 + r) << 3) + (k & 7);
            a_hi[off] = hs;
            a_lo[off] = ls;
        }
        __syncthreads();

        int* prog_me = bar + 256 + p * 16;

        for (int t = 0; t < NSTEP; ++t) {
            // ring-slot throttle: proceed when quarter-3 consumers completed step
            // t-3; transitively (their per-step all-quarter waits) this implies
            // every consumer completed step t-4, i.e. all reads of this slot's
            // previous use are done.
            if (t >= R_GX - 1)
                while (__hip_atomic_load(bar + 48, __ATOMIC_RELAXED,
                                         __HIP_MEMORY_SCOPE_AGENT) < 32 * (t - R_GX + 2))
                    __builtin_amdgcn_s_sleep(4);

            f32x4 acc[2][2];
            #pragma unroll
            for (int a = 0; a < 4; ++a) acc[a >> 1][a & 1] = (f32x4){0.f, 0.f, 0.f, 0.f};

            {
                const ushort_t* xb = xf_hi + (((size_t)t * 16 + kq * 4) * 4 + wn * 2) * 512 + L * 8;
                const ushort_t* xl = xf_lo + (((size_t)t * 16 + kq * 4) * 4 + wn * 2) * 512 + L * 8;
                bf16x8 Bh[2][2], Bl[2][2];
                Bh[0][0] = *(const bf16x8*)(xb);        Bl[0][0] = *(const bf16x8*)(xl);
                Bh[0][1] = *(const bf16x8*)(xb + 512);  Bl[0][1] = *(const bf16x8*)(xl + 512);
                #pragma unroll
                for (int ks = 0; ks < 4; ++ks) {
                    const int cur = ks & 1, nxt = cur ^ 1;
                    if (ks < 3) {
                        const size_t o_ = (size_t)(ks + 1) * 2048;
                        Bh[nxt][0] = *(const bf16x8*)(xb + o_);
                        Bl[nxt][0] = *(const bf16x8*)(xl + o_);
                        Bh[nxt][1] = *(const bf16x8*)(xb + o_ + 512);
                        Bl[nxt][1] = *(const bf16x8*)(xl + o_ + 512);
                    }
                    const int ab = (((kq * 4 + ks) * 2) << 9) + (L << 3);
                    bf16x8 ah0 = *(const bf16x8*)(a_hi + ab);
                    bf16x8 al0 = *(const bf16x8*)(a_lo + ab);
                    bf16x8 ah1 = *(const bf16x8*)(a_hi + ab + 512);
                    bf16x8 al1 = *(const bf16x8*)(a_lo + ab + 512);
                    mfma12(ah0, al0, ah1, al1,
                           Bh[cur][0], Bl[cur][0], Bh[cur][1], Bl[cur][1], acc);
                }
            }

            KREDUCE()

            if (kq == 0) {
                const size_t gb = ((size_t)(t & (R_GX - 1)) * 128 + p) * 8;
                #pragma unroll
                for (int mt = 0; mt < 2; ++mt)
                    #pragma unroll
                    for (int ntl = 0; ntl < 2; ++ntl) {
                        size_t off = ((gb + mt * 4 + q) * 64 + wn * 32 + ntl * 16 + n) * 4;
                        #pragma unroll
                        for (int jj = 0; jj < 2; ++jj) {
                            f32x2 f2 = { acc[mt][ntl][jj * 2], acc[mt][ntl][jj * 2 + 1] };
                            __hip_atomic_store((ull_t*)(gx + off) + jj,
                                __builtin_bit_cast(ull_t, f2),
                                __ATOMIC_RELAXED, __HIP_MEMORY_SCOPE_AGENT);
                        }
                    }
            }
            __syncthreads();   // drain gx stores before publishing
            if (tid == 0)
                __hip_atomic_fetch_add(prog_me, 1, __ATOMIC_RELAXED,
                                       __HIP_MEMORY_SCOPE_AGENT);
        }
    }
}

// out[b][col] = sum over 128 block partials + bias.
__global__ __launch_bounds__(256) void finalize_mfma(
    const float* __restrict__ pout, const float* __restrict__ b_ans,
    float* __restrict__ out)
{
    __shared__ float r[256];
    int col = blockIdx.x;
    int tid = threadIdx.x;
    int b = tid & 63, qq = tid >> 6;
    float s = 0.f;
    for (int i = qq; i < 128; i += 4)
        s += pout[((size_t)col * 128 + i) * 64 + b];
    r[tid] = s;
    __syncthreads();
    if (tid < 64)
        out[tid * NOUT + col] = r[tid] + r[64 + tid] + r[128 + tid] + r[192 + tid]
                              + b_ans[0];
}

// ===================== round-9 proven fallback path =====================
#define NBLK    512
#define NTHR    512
#define REDA_OFF 12288
#define REDB_OFF 14336
#define REDC_OFF 15360
#define C_OFF    15872
#define HEAD_OFF 16000
#define LDS_FLOATS 16128

__global__ __launch_bounds__(256) void init_state(
    const float* __restrict__ h0, const float* __restrict__ c0,
    float* __restrict__ hT, float* __restrict__ cT)
{
    int id = blockIdx.x * 256 + threadIdx.x;
    int u = id >> 6, b = id & 63;
    hT[id] = h0[b * HID + u];
    cT[id] = c0[b * HID + u];
}

__global__ __launch_bounds__(256) void embed_transpose(
    const int* __restrict__ prob, const float* __restrict__ embed,
    float* __restrict__ xT)
{
    __shared__ float xe[64 * 132];
    int t = blockIdx.x;
    int tid = threadIdx.x;
    for (int kt = 0; kt < 4; ++kt) {
        #pragma unroll
        for (int i = 0; i < 8; ++i) {
            int id = tid + i * 256;
            int b  = id >> 5;
            int k4 = id & 31;
            int tok = prob[b * SEQLEN + t];
            float4 v = *(const float4*)(embed + (size_t)tok * EMBED + kt * 128 + k4 * 4);
            *(float4*)(&xe[b * 132 + k4 * 4]) = v;
        }
        __syncthreads();
        #pragma unroll
        for (int i = 0; i < 8; ++i) {
            int id = tid + i * 256;
            int kl = id >> 4;
            int b4 = id & 15;
            float4 v;
            v.x = xe[(b4 * 4 + 0) * 132 + kl];
            v.y = xe[(b4 * 4 + 1) * 132 + kl];
            v.z = xe[(b4 * 4 + 2) * 132 + kl];
            v.w = xe[(b4 * 4 + 3) * 132 + kl];
            *(float4*)(&xT[((size_t)t * EMBED + kt * 128 + kl) * 64 + b4 * 4]) = v;
        }
        __syncthreads();
    }
}

__global__ __launch_bounds__(NTHR, 4) void lstm_persist_hist(
    const float* __restrict__ xT, float* __restrict__ h_hist,
    const float* __restrict__ cT,
    const float* __restrict__ w_ih, const float* __restrict__ w_hh,
    const float* __restrict__ b_ih, const float* __restrict__ b_hh,
    const float* __restrict__ w_ans, float* __restrict__ pout,
    int* __restrict__ bar)
{
    __shared__ float lds[LDS_FLOATS];
    const int tid = threadIdx.x;
    const int bid = blockIdx.x;
    const int b   = tid & 63;
    const int ksl = __builtin_amdgcn_readfirstlane(tid >> 6);
    const int u0  = bid * 2;

    int* sliceCnt = bar + (bid >> 6) * 32;
    int* mySlice  = bar + 256 + (bid >> 6) * 32;
    int* waitGo   = bar + 256 + ksl * 32;

    for (int idx = tid; idx < 12288; idx += NTHR) {
        int r  = idx / 1536;
        int k  = idx - r * 1536;
        int u2 = r & 1, gate = r >> 1;
        int row = gate * HID + u0 + u2;
        float v = (k < EMBED) ? w_ih[(size_t)row * EMBED + k]
                              : w_hh[(size_t)row * HID + (k - EMBED)];
        lds[(u2 * 1536 + k) * 4 + gate] = v;
    }
    if (tid < 128) lds[C_OFF + tid] = cT[u0 * 64 + tid];

    float bias[2][4], wans[2];
    #pragma unroll
    for (int uu = 0; uu < 2; ++uu) {
        #pragma unroll
        for (int j = 0; j < 4; ++j) {
            int rj = j * HID + u0 + uu;
            bias[uu][j] = b_ih[rj] + b_hh[rj];
        }
        wans[uu] = w_ans[u0 + uu];
    }
    __syncthreads();

    for (int t = 0; t < NSTEP; ++t) {
        const float* xt = xT + (size_t)t * EMBED * 64;
        const float* ht = h_hist + (size_t)t * HID * 64;
        float* hn_buf   = h_hist + (size_t)(t + 1) * HID * 64;

        float acc[2][4];
        #pragma unroll
        for (int uu = 0; uu < 2; ++uu)
            #pragma unroll
            for (int j = 0; j < 4; ++j) acc[uu][j] = 0.f;

        const int kx0 = ksl * 64;
        #pragma unroll 4
        for (int g = 0; g < 16; ++g) {
            const int k = kx0 + g * 4;
            float xv[4];
            #pragma unroll
            for (int i = 0; i < 4; ++i) xv[i] = xt[(size_t)(k + i) * 64 + b];
            #pragma unroll
            for (int i = 0; i < 4; ++i) {
                float4 wa = *(const float4*)&lds[(0 * 1536 + k + i) * 4];
                float4 wb = *(const float4*)&lds[(1 * 1536 + k + i) * 4];
                acc[0][0] = fmaf(wa.x, xv[i], acc[0][0]);
                acc[0][1] = fmaf(wa.y, xv[i], acc[0][1]);
                acc[0][2] = fmaf(wa.z, xv[i], acc[0][2]);
                acc[0][3] = fmaf(wa.w, xv[i], acc[0][3]);
                acc[1][0] = fmaf(wb.x, xv[i], acc[1][0]);
                acc[1][1] = fmaf(wb.y, xv[i], acc[1][1]);
                acc[1][2] = fmaf(wb.z, xv[i], acc[1][2]);
                acc[1][3] = fmaf(wb.w, xv[i], acc[1][3]);
            }
        }

        if (t > 0) {
            while (__hip_atomic_load(waitGo, __ATOMIC_RELAXED,
                                     __HIP_MEMORY_SCOPE_AGENT) < t)
                __builtin_amdgcn_s_sleep(4);
            __builtin_amdgcn_fence(__ATOMIC_ACQUIRE, "workgroup");
        }

        const int kh0 = ksl * 128;
        #pragma unroll 4
        for (int g = 0; g < 32; ++g) {
            const int kh = kh0 + g * 4;
            float hv[4];
            #pragma unroll
            for (int i = 0; i < 4; ++i)
                hv[i] = ht[(size_t)(kh + i) * 64 + b];
            #pragma unroll
            for (int i = 0; i < 4; ++i) {
                const int kw = EMBED + kh + i;
                float4 wa = *(const float4*)&lds[(0 * 1536 + kw) * 4];
                float4 wb = *(const float4*)&lds[(1 * 1536 + kw) * 4];
                acc[0][0] = fmaf(wa.x, hv[i], acc[0][0]);
                acc[0][1] = fmaf(wa.y, hv[i], acc[0][1]);
                acc[0][2] = fmaf(wa.z, hv[i], acc[0][2]);
                acc[0][3] = fmaf(wa.w, hv[i], acc[0][3]);
                acc[1][0] = fmaf(wb.x, hv[i], acc[1][0]);
                acc[1][1] = fmaf(wb.y, hv[i], acc[1][1]);
                acc[1][2] = fmaf(wb.z, hv[i], acc[1][2]);
                acc[1][3] = fmaf(wb.w, hv[i], acc[1][3]);
            }
        }

        if (ksl >= 4) {
            #pragma unroll
            for (int uu = 0; uu < 2; ++uu)
                #pragma unroll
                for (int j = 0; j < 4; ++j)
                    lds[REDA_OFF + (((ksl - 4) * 8) + uu * 4 + j) * 64 + b] = acc[uu][j];
        }
        __syncthreads();
        if (ksl < 4) {
            #pragma unroll
            for (int uu = 0; uu < 2; ++uu)
                #pragma unroll
                for (int j = 0; j < 4; ++j)
                    acc[uu][j] += lds[REDA_OFF + ((ksl * 8) + uu * 4 + j) * 64 + b];
        }
        if (ksl == 2 || ksl == 3) {
            #pragma unroll
            for (int uu = 0; uu < 2; ++uu)
                #pragma unroll
                for (int j = 0; j < 4; ++j)
                    lds[REDB_OFF + (((ksl - 2) * 8) + uu * 4 + j) * 64 + b] = acc[uu][j];
        }
        __syncthreads();
        if (ksl < 2) {
            #pragma unroll
            for (int uu = 0; uu < 2; ++uu)
                #pragma unroll
                for (int j = 0; j < 4; ++j)
                    acc[uu][j] += lds[REDB_OFF + ((ksl * 8) + uu * 4 + j) * 64 + b];
        }
        if (ksl == 0) {
            #pragma unroll
            for (int j = 0; j < 4; ++j)
                lds[REDC_OFF + j * 64 + b] = acc[1][j];
        }
        if (ksl == 1) {
            #pragma unroll
            for (int j = 0; j < 4; ++j)
                lds[REDC_OFF + (4 + j) * 64 + b] = acc[0][j];
        }
        __syncthreads();
        if (ksl < 2) {
            const int uu = ksl;
            float s[4];
            if (ksl == 0) {
                #pragma unroll
                for (int j = 0; j < 4; ++j)
                    s[j] = acc[0][j] + lds[REDC_OFF + (4 + j) * 64 + b];
            } else {
                #pragma unroll
                for (int j = 0; j < 4; ++j)
                    s[j] = acc[1][j] + lds[REDC_OFF + j * 64 + b];
            }
            float i_g = sigmoidf_(s[0] + bias[uu][0]);
            float f_g = sigmoidf_(s[1] + bias[uu][1]);
            float g_g = tanhf   (s[2] + bias[uu][2]);
            float o_g = sigmoidf_(s[3] + bias[uu][3]);
            float c_old = lds[C_OFF + uu * 64 + b];
            float c_new = f_g * c_old + i_g * g_g;
            float h_new = o_g * tanhf(c_new);
            lds[C_OFF + uu * 64 + b] = c_new;
            __hip_atomic_store(&hn_buf[(u0 + uu) * 64 + b], h_new,
                               __ATOMIC_RELAXED, __HIP_MEMORY_SCOPE_AGENT);
            lds[HEAD_OFF + uu * 64 + b] = h_new * wans[uu];
        }

        __syncthreads();
        if (t >= OUT0 && tid < 64) {
            pout[((size_t)(t - OUT0) * NBLK + bid) * 64 + tid] =
                lds[HEAD_OFF + tid] + lds[HEAD_OFF + 64 + tid];
        }
        if (t == NSTEP - 1) break;
        if (tid == 0) {
            int r = __hip_atomic_fetch_add(sliceCnt, 1, __ATOMIC_RELAXED,
                                           __HIP_MEMORY_SCOPE_AGENT);
            if (r == 64 * (t + 1) - 1)
                __hip_atomic_store(mySlice, t + 1, __ATOMIC_RELAXED,
                                   __HIP_MEMORY_SCOPE_AGENT);
        }
    }
}

__global__ __launch_bounds__(256) void finalize_persist(
    const float* __restrict__ pout, const float* __restrict__ b_ans,
    float* __restrict__ out)
{
    __shared__ float r[256];
    int col = blockIdx.x;
    int tid = threadIdx.x;
    int b = tid & 63, qq = tid >> 6;
    float s = 0.f;
    for (int i = qq; i < NBLK; i += 4)
        s += pout[((size_t)col * NBLK + i) * 64 + b];
    r[tid] = s;
    __syncthreads();
    if (tid < 64)
        out[tid * NOUT + col] = r[tid] + r[64 + tid] + r[128 + tid] + r[192 + tid]
                              + b_ans[0];
}

extern "C" void kernel_launch(void* const* d_in, const int* in_sizes, int n_in,
                              void* d_out, int out_size, void* d_ws, size_t ws_size,
                              hipStream_t stream)
{
    const int*   prob  = (const int*)  d_in[0];
    const float* embed = (const float*)d_in[2];
    const float* w_ih  = (const float*)d_in[3];
    const float* w_hh  = (const float*)d_in[4];
    const float* b_ih  = (const float*)d_in[5];
    const float* b_hh  = (const float*)d_in[6];
    const float* w_ans = (const float*)d_in[7];
    const float* b_ans = (const float*)d_in[8];
    const float* h0    = (const float*)d_in[9];
    const float* c0    = (const float*)d_in[10];

    // ---- fused-path ws layout (bytes), total 56,705,024 < proven 58.6 MB ----
    char* W = (char*)d_ws;
    float*    cT_m  = (float*)   (W);              //   262,144 B
    float*    poutm = (float*)   (W + 262144);     // 2,031,616 B  (62 x 128 x 64 f32)
    ushort_t* xf_hi = (ushort_t*)(W + 2293760);    // 8,323,072 B
    ushort_t* xf_lo = (ushort_t*)(W + 10616832);   // 8,323,072 B
    ushort_t* hf_hi = (ushort_t*)(W + 18939904);   // 16,777,216 B (full per-t history)
    ushort_t* hf_lo = (ushort_t*)(W + 35717120);   // 16,777,216 B
    float*    gx    = (float*)   (W + 52494336);   // 4,194,304 B  (R_GX=4 ring)
    int*      bar_m = (int*)     (W + 56688640);   //    16,384 B

    const int DYN_LDS = 155648;    // a_hi 64K + a_lo 64K + reduce 24K

    hipError_t err = hipFuncSetAttribute(
        (const void*)lstm_fused,
        hipFuncAttributeMaxDynamicSharedMemorySize, DYN_LDS);

    if (err == hipSuccess) {
        hipMemsetAsync(bar_m, 0, 16384, stream);
        init_mfma<<<256, 256, 0, stream>>>(h0, c0, cT_m, hf_hi, hf_lo);
        embed_frag<<<NSTEP, 256, 0, stream>>>(prob, embed, xf_hi, xf_lo);

        void* args[] = {
            (void*)&xf_hi, (void*)&xf_lo, (void*)&hf_hi, (void*)&hf_lo,
            (void*)&cT_m, (void*)&w_ih, (void*)&w_hh, (void*)&b_ih,
            (void*)&b_hh, (void*)&w_ans, (void*)&poutm, (void*)&gx, (void*)&bar_m
        };
        err = hipLaunchCooperativeKernel((const void*)lstm_fused,
                                         dim3(256), dim3(512),
                                         args, DYN_LDS, stream);
        if (err == hipSuccess) {
            finalize_mfma<<<NOUT, 256, 0, stream>>>(poutm, b_ans, (float*)d_out);
            return;
        }
    }

    // ---- fallback: round-9 proven path (aliases the same ws region) ----
    float* ws     = (float*)d_ws;
    float* cT     = ws;                    // 65,536 fl
    float* pout   = ws + 65536;            // 2,031,616 fl
    float* xT     = ws + 2097152;          // 4,161,536 fl
    float* h_hist = ws + 6258688;          // 8,388,608 fl
    int*   bar    = (int*)(ws + 14647296);

    hipMemsetAsync(bar, 0, 2048, stream);
    init_state<<<256, 256, 0, stream>>>(h0, c0, h_hist, cT);
    embed_transpose<<<NSTEP, 256, 0, stream>>>(prob, embed, xT);

    void* args9[] = {
        (void*)&xT, (void*)&h_hist, (void*)&cT,
        (void*)&w_ih, (void*)&w_hh, (void*)&b_ih, (void*)&b_hh,
        (void*)&w_ans, (void*)&pout, (void*)&bar
    };
    hipLaunchCooperativeKernel((const void*)lstm_persist_hist,
                               dim3(NBLK), dim3(NTHR), args9, 0, stream);
    finalize_persist<<<NOUT, 256, 0, stream>>>(pout, b_ans, (float*)d_out);
}

// Round 4
// 865.153 us; speedup vs baseline: 2.0392x; 2.0392x over previous
//
#include <hip/hip_runtime.h>
#include <math.h>

#define BATCH   64
#define SEQLEN  128
#define EMBED   512
#define HID     1024
#define NSTEP   127
#define OUT0    65
#define NOUT    62

typedef unsigned short ushort_t;
typedef __attribute__((ext_vector_type(8))) __bf16 bf16x8;
typedef __attribute__((ext_vector_type(4))) float  f32x4;

__device__ __forceinline__ float sigmoidf_(float x) { return 1.f / (1.f + expf(-x)); }

__device__ __forceinline__ ushort_t f2bf(float f) {
    unsigned u = __builtin_bit_cast(unsigned, f);
    unsigned r = (u + 0x7FFFu + ((u >> 16) & 1u)) >> 16;   // round-to-nearest-even
    return (ushort_t)r;
}
__device__ __forceinline__ float bf2f(ushort_t s) {
    unsigned u = ((unsigned)s) << 16;
    return __builtin_bit_cast(float, u);
}

// ===================== MFMA path prep =====================

__global__ __launch_bounds__(256) void init_mfma(
    const float* __restrict__ h0, const float* __restrict__ c0,
    float* __restrict__ cT, ushort_t* __restrict__ hf_hi, ushort_t* __restrict__ hf_lo)
{
    int id = blockIdx.x * 256 + threadIdx.x;   // u*64+b
    int u = id >> 6, b = id & 63;
    cT[id] = c0[b * HID + u];
    float h = h0[b * HID + u];
    ushort_t hs = f2bf(h);
    ushort_t ls = f2bf(h - bf2f(hs));
    size_t idx = (((size_t)(u >> 5)) * 4 + (b >> 4)) * 512
               + ((((u & 31) >> 3) * 16) + (b & 15)) * 8 + (u & 7);
    hf_hi[idx] = hs;
    hf_lo[idx] = ls;
}

// coalesced — thread = (b, k-block-of-8); frag layout keeps k&7 contiguous so
// each thread writes two 16B bf16x8 stores.
__global__ __launch_bounds__(256) void embed_frag(
    const int* __restrict__ prob, const float* __restrict__ embed,
    ushort_t* __restrict__ xf_hi, ushort_t* __restrict__ xf_lo)
{
    int t = blockIdx.x;
    for (int e = threadIdx.x; e < 4096; e += 256) {
        int b  = e >> 6;         // 0..63
        int kb = e & 63;         // k-block of 8
        int k  = kb * 8;
        int tok = prob[b * SEQLEN + t];
        const float* row = embed + (size_t)tok * EMBED + k;
        float4 f0 = *(const float4*)(row);
        float4 f1 = *(const float4*)(row + 4);
        float fv[8] = { f0.x, f0.y, f0.z, f0.w, f1.x, f1.y, f1.z, f1.w };
        bf16x8 hv, lv;
        #pragma unroll
        for (int i = 0; i < 8; ++i) {
            ushort_t hs = f2bf(fv[i]);
            ushort_t ls = f2bf(fv[i] - bf2f(hs));
            hv[i] = __builtin_bit_cast(__bf16, hs);
            lv[i] = __builtin_bit_cast(__bf16, ls);
        }
        size_t idx = (((size_t)t * 16 + (kb >> 2)) * 4 + (b >> 4)) * 512
                   + (((kb & 3) * 16) + (b & 15)) * 8;
        *(bf16x8*)(xf_hi + idx) = hv;
        *(bf16x8*)(xf_lo + idx) = lv;
    }
}

// ===================== MFMA persistent kernel (r13 structure + per-quarter sync) =====
// 256 blocks x 1024 thr (1 block/CU, 16 waves = 48% occ). Block = 4 units =
// 16 gate-rows (MFMA M-tile). Wave w: N-tile wn=w&3, K-quarter kq=w>>2.
// Per wave: x 4 ksteps, h 8 ksteps, x3 MFMA (bf16x3), 1-deep B prefetch.
// Binary reduce: kq>=2 -> REDA, kq1 -> REDB, kq0 finalizes in-lane.
// r4 change (ONLY delta vs the measured-902.5us kernel): the two-level
// cnt->scnt->go handshake (3 serialized L3 hops, waits on ALL 256 blocks) is
// replaced by per-K-quarter arrival counters: block bid increments
// bar[(bid>>6)*32] once per step; wave kq spins on bar[kq*32] >= 64*t.
// Mechanism: 2 fewer serialized hops per step, and each wave starts its
// h-GEMM as soon as ITS quarter's 64 producer-blocks finish (skew -> overlap
// instead of global max). Pattern (store -> syncthreads(vmcnt0) -> relaxed
// agent atomic / relaxed spin + acquire fence) is identical to the scheme
// harness-verified in r1/r2/r13.
__global__ __launch_bounds__(1024) void lstm_mfma(
    const ushort_t* __restrict__ xf_hi, const ushort_t* __restrict__ xf_lo,
    ushort_t* __restrict__ hf_hi, ushort_t* __restrict__ hf_lo,
    const float* __restrict__ cT,
    const float* __restrict__ w_ih, const float* __restrict__ w_hh,
    const float* __restrict__ b_ih, const float* __restrict__ b_hh,
    const float* __restrict__ w_ans, float* __restrict__ pout,
    int* __restrict__ bar)
{
    extern __shared__ ushort_t smem[];
    ushort_t* a_hi = smem;                       // [ks 48][512] 48 KB
    ushort_t* a_lo = smem + 48 * 512;            // 48 KB
    float*    redA = (float*)(smem + 96 * 512);  // 8 KB (8 waves x 64 x f32x4)
    float*    redB = redA + 2048;                // 4 KB (4 waves x 64 x f32x4)

    const int tid = threadIdx.x;
    const int bid = blockIdx.x;
    const int w   = tid >> 6;        // 0..15
    const int wn  = w & 3;           // N-tile
    const int kq  = w >> 2;          // K-quarter 0..3
    const int L   = tid & 63;
    const int n   = L & 15;
    const int q   = L >> 4;
    const int u0  = bid * 4;
    const int ug  = u0 + q;
    const int bg  = wn * 16 + n;

    // per-quarter arrival counters, 128 B apart
    int* gc_me   = bar + kq * 32;            // wave's wait target
    int* gc_mine = bar + (bid >> 6) * 32;    // this block's arrival counter

    // ---- one-time: weight split -> A-frag LDS image ----
    for (int m = 0; m < 16; ++m) {
        int unit = m >> 2, gate = m & 3;
        size_t rowg = (size_t)gate * HID + u0 + unit;
        for (int k = tid; k < 1536; k += 1024) {
            float f = (k < EMBED) ? w_ih[rowg * EMBED + k]
                                  : w_hh[rowg * HID + (k - EMBED)];
            ushort_t hs = f2bf(f);
            ushort_t ls = f2bf(f - bf2f(hs));
            int off = (k >> 5) * 512 + (((k & 31) >> 3) * 16 + m) * 8 + (k & 7);
            a_hi[off] = hs;
            a_lo[off] = ls;
        }
    }

    float c = cT[ug * 64 + bg];
    float bs[4];
    #pragma unroll
    for (int j = 0; j < 4; ++j) bs[j] = b_ih[j * HID + ug] + b_hh[j * HID + ug];
    const float wansu = w_ans[ug];
    __syncthreads();

    for (int t = 0; t < NSTEP; ++t) {
        f32x4 acc = {0.f, 0.f, 0.f, 0.f};

        // ---- x phase: this wave's 4 ksteps (independent of h(t-1)) ----
        {
            const ushort_t* xh = xf_hi + (((size_t)t * 16 + kq * 4) * 4 + wn) * 512 + L * 8;
            const ushort_t* xl = xf_lo + (((size_t)t * 16 + kq * 4) * 4 + wn) * 512 + L * 8;
            bf16x8 bh = *(const bf16x8*)(xh);
            bf16x8 bl = *(const bf16x8*)(xl);
            #pragma unroll
            for (int ks = 0; ks < 4; ++ks) {
                bf16x8 bh1, bl1;
                if (ks < 3) {
                    bh1 = *(const bf16x8*)(xh + (size_t)(ks + 1) * 2048);
                    bl1 = *(const bf16x8*)(xl + (size_t)(ks + 1) * 2048);
                }
                bf16x8 ah = *(const bf16x8*)(a_hi + (kq * 4 + ks) * 512 + L * 8);
                bf16x8 al = *(const bf16x8*)(a_lo + (kq * 4 + ks) * 512 + L * 8);
                acc = __builtin_amdgcn_mfma_f32_16x16x32_bf16(ah, bh, acc, 0, 0, 0);
                acc = __builtin_amdgcn_mfma_f32_16x16x32_bf16(al, bh, acc, 0, 0, 0);
                acc = __builtin_amdgcn_mfma_f32_16x16x32_bf16(ah, bl, acc, 0, 0, 0);
                bh = bh1; bl = bl1;
            }
        }

        // ---- wait for THIS K-quarter of h(t): read-only spin (no cache inv) ----
        if (t > 0) {
            const int need = 64 * t;
            while (__hip_atomic_load(gc_me, __ATOMIC_RELAXED,
                                     __HIP_MEMORY_SCOPE_AGENT) < need)
                __builtin_amdgcn_s_sleep(1);
            __builtin_amdgcn_fence(__ATOMIC_ACQUIRE, "workgroup");
        }

        // ---- h phase: this wave's 8 ksteps, 1-deep prefetch ----
        {
            const ushort_t* hh = hf_hi + (((size_t)t * 32 + kq * 8) * 4 + wn) * 512 + L * 8;
            const ushort_t* hl = hf_lo + (((size_t)t * 32 + kq * 8) * 4 + wn) * 512 + L * 8;
            bf16x8 bh = *(const bf16x8*)(hh);
            bf16x8 bl = *(const bf16x8*)(hl);
            #pragma unroll
            for (int ks = 0; ks < 8; ++ks) {
                bf16x8 bh1, bl1;
                if (ks < 7) {
                    bh1 = *(const bf16x8*)(hh + (size_t)(ks + 1) * 2048);
                    bl1 = *(const bf16x8*)(hl + (size_t)(ks + 1) * 2048);
                }
                bf16x8 ah = *(const bf16x8*)(a_hi + (16 + kq * 8 + ks) * 512 + L * 8);
                bf16x8 al = *(const bf16x8*)(a_lo + (16 + kq * 8 + ks) * 512 + L * 8);
                acc = __builtin_amdgcn_mfma_f32_16x16x32_bf16(ah, bh, acc, 0, 0, 0);
                acc = __builtin_amdgcn_mfma_f32_16x16x32_bf16(al, bh, acc, 0, 0, 0);
                acc = __builtin_amdgcn_mfma_f32_16x16x32_bf16(ah, bl, acc, 0, 0, 0);
                bh = bh1; bl = bl1;
            }
        }

        // ---- K reduce: kq>=2 -> REDA; kq<2 add; kq1 -> REDB; kq0 adds ----
        if (kq >= 2)
            *(f32x4*)(redA + ((w - 8) * 64 + L) * 4) = acc;
        __syncthreads();
        if (kq < 2) {
            f32x4 r = *(const f32x4*)(redA + (w * 64 + L) * 4);  // (wn,kq) <- (wn,kq+2)
            acc += r;
        }
        if (kq == 1)
            *(f32x4*)(redB + ((w - 4) * 64 + L) * 4) = acc;
        __syncthreads();

        if (kq == 0) {
            f32x4 r = *(const f32x4*)(redB + (w * 64 + L) * 4);
            acc += r;

            // ---- finalize in-lane: lane owns (unit ug, batch bg) ----
            float ig = sigmoidf_(acc[0] + bs[0]);
            float fg = sigmoidf_(acc[1] + bs[1]);
            float gg = tanhf    (acc[2] + bs[2]);
            float og = sigmoidf_(acc[3] + bs[3]);
            c = fg * c + ig * gg;
            float h_new = og * tanhf(c);

            float p = h_new * wansu;
            p += __shfl_xor(p, 16, 64);
            p += __shfl_xor(p, 32, 64);
            if (t >= OUT0 && q == 0)
                pout[((size_t)(t - OUT0) * 256 + bid) * 64 + bg] = p;

            ushort_t hs = f2bf(h_new);
            ushort_t ls = f2bf(h_new - bf2f(hs));
            int kr = ug & 31, hks = ug >> 5;
            size_t idx = (((size_t)(t + 1) * 32 + hks) * 4 + wn) * 512
                       + (((kr >> 3) * 16) + n) * 8 + (kr & 7);
            __hip_atomic_store(&hf_hi[idx], hs, __ATOMIC_RELAXED,
                               __HIP_MEMORY_SCOPE_AGENT);
            __hip_atomic_store(&hf_lo[idx], ls, __ATOMIC_RELAXED,
                               __HIP_MEMORY_SCOPE_AGENT);
        }

        if (t == NSTEP - 1) break;

        __syncthreads();   // drains producer stores (vmcnt 0) before arrive
        if (tid == 0)
            __hip_atomic_fetch_add(gc_mine, 1, __ATOMIC_RELAXED,
                                   __HIP_MEMORY_SCOPE_AGENT);
    }
}

// out[b][col] = sum over 256 block partials + bias.
__global__ __launch_bounds__(256) void finalize_mfma(
    const float* __restrict__ pout, const float* __restrict__ b_ans,
    float* __restrict__ out)
{
    __shared__ float r[256];
    int col = blockIdx.x;
    int tid = threadIdx.x;
    int b = tid & 63, qq = tid >> 6;
    float s = 0.f;
    for (int i = qq; i < 256; i += 4)
        s += pout[((size_t)col * 256 + i) * 64 + b];
    r[tid] = s;
    __syncthreads();
    if (tid < 64)
        out[tid * NOUT + col] = r[tid] + r[64 + tid] + r[128 + tid] + r[192 + tid]
                              + b_ans[0];
}

// ===================== round-9 proven fallback path =====================
#define NBLK    512
#define NTHR    512
#define REDA_OFF 12288
#define REDB_OFF 14336
#define REDC_OFF 15360
#define C_OFF    15872
#define HEAD_OFF 16000
#define LDS_FLOATS 16128

__global__ __launch_bounds__(256) void init_state(
    const float* __restrict__ h0, const float* __restrict__ c0,
    float* __restrict__ hT, float* __restrict__ cT)
{
    int id = blockIdx.x * 256 + threadIdx.x;
    int u = id >> 6, b = id & 63;
    hT[id] = h0[b * HID + u];
    cT[id] = c0[b * HID + u];
}

__global__ __launch_bounds__(256) void embed_transpose(
    const int* __restrict__ prob, const float* __restrict__ embed,
    float* __restrict__ xT)
{
    __shared__ float xe[64 * 132];
    int t = blockIdx.x;
    int tid = threadIdx.x;
    for (int kt = 0; kt < 4; ++kt) {
        #pragma unroll
        for (int i = 0; i < 8; ++i) {
            int id = tid + i * 256;
            int b  = id >> 5;
            int k4 = id & 31;
            int tok = prob[b * SEQLEN + t];
            float4 v = *(const float4*)(embed + (size_t)tok * EMBED + kt * 128 + k4 * 4);
            *(float4*)(&xe[b * 132 + k4 * 4]) = v;
        }
        __syncthreads();
        #pragma unroll
        for (int i = 0; i < 8; ++i) {
            int id = tid + i * 256;
            int kl = id >> 4;
            int b4 = id & 15;
            float4 v;
            v.x = xe[(b4 * 4 + 0) * 132 + kl];
            v.y = xe[(b4 * 4 + 1) * 132 + kl];
            v.z = xe[(b4 * 4 + 2) * 132 + kl];
            v.w = xe[(b4 * 4 + 3) * 132 + kl];
            *(float4*)(&xT[((size_t)t * EMBED + kt * 128 + kl) * 64 + b4 * 4]) = v;
        }
        __syncthreads();
    }
}

__global__ __launch_bounds__(NTHR, 4) void lstm_persist_hist(
    const float* __restrict__ xT, float* __restrict__ h_hist,
    const float* __restrict__ cT,
    const float* __restrict__ w_ih, const float* __restrict__ w_hh,
    const float* __restrict__ b_ih, const float* __restrict__ b_hh,
    const float* __restrict__ w_ans, float* __restrict__ pout,
    int* __restrict__ bar)
{
    __shared__ float lds[LDS_FLOATS];
    const int tid = threadIdx.x;
    const int bid = blockIdx.x;
    const int b   = tid & 63;
    const int ksl = __builtin_amdgcn_readfirstlane(tid >> 6);
    const int u0  = bid * 2;

    int* sliceCnt = bar + (bid >> 6) * 32;
    int* mySlice  = bar + 256 + (bid >> 6) * 32;
    int* waitGo   = bar + 256 + ksl * 32;

    for (int idx = tid; idx < 12288; idx += NTHR) {
        int r  = idx / 1536;
        int k  = idx - r * 1536;
        int u2 = r & 1, gate = r >> 1;
        int row = gate * HID + u0 + u2;
        float v = (k < EMBED) ? w_ih[(size_t)row * EMBED + k]
                              : w_hh[(size_t)row * HID + (k - EMBED)];
        lds[(u2 * 1536 + k) * 4 + gate] = v;
    }
    if (tid < 128) lds[C_OFF + tid] = cT[u0 * 64 + tid];

    float bias[2][4], wans[2];
    #pragma unroll
    for (int uu = 0; uu < 2; ++uu) {
        #pragma unroll
        for (int j = 0; j < 4; ++j) {
            int rj = j * HID + u0 + uu;
            bias[uu][j] = b_ih[rj] + b_hh[rj];
        }
        wans[uu] = w_ans[u0 + uu];
    }
    __syncthreads();

    for (int t = 0; t < NSTEP; ++t) {
        const float* xt = xT + (size_t)t * EMBED * 64;
        const float* ht = h_hist + (size_t)t * HID * 64;
        float* hn_buf   = h_hist + (size_t)(t + 1) * HID * 64;

        float acc[2][4];
        #pragma unroll
        for (int uu = 0; uu < 2; ++uu)
            #pragma unroll
            for (int j = 0; j < 4; ++j) acc[uu][j] = 0.f;

        const int kx0 = ksl * 64;
        #pragma unroll 4
        for (int g = 0; g < 16; ++g) {
            const int k = kx0 + g * 4;
            float xv[4];
            #pragma unroll
            for (int i = 0; i < 4; ++i) xv[i] = xt[(size_t)(k + i) * 64 + b];
            #pragma unroll
            for (int i = 0; i < 4; ++i) {
                float4 wa = *(const float4*)&lds[(0 * 1536 + k + i) * 4];
                float4 wb = *(const float4*)&lds[(1 * 1536 + k + i) * 4];
                acc[0][0] = fmaf(wa.x, xv[i], acc[0][0]);
                acc[0][1] = fmaf(wa.y, xv[i], acc[0][1]);
                acc[0][2] = fmaf(wa.z, xv[i], acc[0][2]);
                acc[0][3] = fmaf(wa.w, xv[i], acc[0][3]);
                acc[1][0] = fmaf(wb.x, xv[i], acc[1][0]);
                acc[1][1] = fmaf(wb.y, xv[i], acc[1][1]);
                acc[1][2] = fmaf(wb.z, xv[i], acc[1][2]);
                acc[1][3] = fmaf(wb.w, xv[i], acc[1][3]);
            }
        }

        if (t > 0) {
            while (__hip_atomic_load(waitGo, __ATOMIC_RELAXED,
                                     __HIP_MEMORY_SCOPE_AGENT) < t)
                __builtin_amdgcn_s_sleep(4);
            __builtin_amdgcn_fence(__ATOMIC_ACQUIRE, "workgroup");
        }

        const int kh0 = ksl * 128;
        #pragma unroll 4
        for (int g = 0; g < 32; ++g) {
            const int kh = kh0 + g * 4;
            float hv[4];
            #pragma unroll
            for (int i = 0; i < 4; ++i)
                hv[i] = ht[(size_t)(kh + i) * 64 + b];
            #pragma unroll
            for (int i = 0; i < 4; ++i) {
                const int kw = EMBED + kh + i;
                float4 wa = *(const float4*)&lds[(0 * 1536 + kw) * 4];
                float4 wb = *(const float4*)&lds[(1 * 1536 + kw) * 4];
                acc[0][0] = fmaf(wa.x, hv[i], acc[0][0]);
                acc[0][1] = fmaf(wa.y, hv[i], acc[0][1]);
                acc[0][2] = fmaf(wa.z, hv[i], acc[0][2]);
                acc[0][3] = fmaf(wa.w, hv[i], acc[0][3]);
                acc[1][0] = fmaf(wb.x, hv[i], acc[1][0]);
                acc[1][1] = fmaf(wb.y, hv[i], acc[1][1]);
                acc[1][2] = fmaf(wb.z, hv[i], acc[1][2]);
                acc[1][3] = fmaf(wb.w, hv[i], acc[1][3]);
            }
        }

        if (ksl >= 4) {
            #pragma unroll
            for (int uu = 0; uu < 2; ++uu)
                #pragma unroll
                for (int j = 0; j < 4; ++j)
                    lds[REDA_OFF + (((ksl - 4) * 8) + uu * 4 + j) * 64 + b] = acc[uu][j];
        }
        __syncthreads();
        if (ksl < 4) {
            #pragma unroll
            for (int uu = 0; uu < 2; ++uu)
                #pragma unroll
                for (int j = 0; j < 4; ++j)
                    acc[uu][j] += lds[REDA_OFF + ((ksl * 8) + uu * 4 + j) * 64 + b];
        }
        if (ksl == 2 || ksl == 3) {
            #pragma unroll
            for (int uu = 0; uu < 2; ++uu)
                #pragma unroll
                for (int j = 0; j < 4; ++j)
                    lds[REDB_OFF + (((ksl - 2) * 8) + uu * 4 + j) * 64 + b] = acc[uu][j];
        }
        __syncthreads();
        if (ksl < 2) {
            #pragma unroll
            for (int uu = 0; uu < 2; ++uu)
                #pragma unroll
                for (int j = 0; j < 4; ++j)
                    acc[uu][j] += lds[REDB_OFF + ((ksl * 8) + uu * 4 + j) * 64 + b];
        }
        if (ksl == 0) {
            #pragma unroll
            for (int j = 0; j < 4; ++j)
                lds[REDC_OFF + j * 64 + b] = acc[1][j];
        }
        if (ksl == 1) {
            #pragma unroll
            for (int j = 0; j < 4; ++j)
                lds[REDC_OFF + (4 + j) * 64 + b] = acc[0][j];
        }
        __syncthreads();
        if (ksl < 2) {
            const int uu = ksl;
            float s[4];
            if (ksl == 0) {
                #pragma unroll
                for (int j = 0; j < 4; ++j)
                    s[j] = acc[0][j] + lds[REDC_OFF + (4 + j) * 64 + b];
            } else {
                #pragma unroll
                for (int j = 0; j < 4; ++j)
                    s[j] = acc[1][j] + lds[REDC_OFF + j * 64 + b];
            }
            float i_g = sigmoidf_(s[0] + bias[uu][0]);
            float f_g = sigmoidf_(s[1] + bias[uu][1]);
            float g_g = tanhf   (s[2] + bias[uu][2]);
            float o_g = sigmoidf_(s[3] + bias[uu][3]);
            float c_old = lds[C_OFF + uu * 64 + b];
            float c_new = f_g * c_old + i_g * g_g;
            float h_new = o_g * tanhf(c_new);
            lds[C_OFF + uu * 64 + b] = c_new;
            __hip_atomic_store(&hn_buf[(u0 + uu) * 64 + b], h_new,
                               __ATOMIC_RELAXED, __HIP_MEMORY_SCOPE_AGENT);
            lds[HEAD_OFF + uu * 64 + b] = h_new * wans[uu];
        }

        __syncthreads();
        if (t >= OUT0 && tid < 64) {
            pout[((size_t)(t - OUT0) * NBLK + bid) * 64 + tid] =
                lds[HEAD_OFF + tid] + lds[HEAD_OFF + 64 + tid];
        }
        if (t == NSTEP - 1) break;
        if (tid == 0) {
            int r = __hip_atomic_fetch_add(sliceCnt, 1, __ATOMIC_RELAXED,
                                           __HIP_MEMORY_SCOPE_AGENT);
            if (r == 64 * (t + 1) - 1)
                __hip_atomic_store(mySlice, t + 1, __ATOMIC_RELAXED,
                                   __HIP_MEMORY_SCOPE_AGENT);
        }
    }
}

__global__ __launch_bounds__(256) void finalize_persist(
    const float* __restrict__ pout, const float* __restrict__ b_ans,
    float* __restrict__ out)
{
    __shared__ float r[256];
    int col = blockIdx.x;
    int tid = threadIdx.x;
    int b = tid & 63, qq = tid >> 6;
    float s = 0.f;
    for (int i = qq; i < NBLK; i += 4)
        s += pout[((size_t)col * NBLK + i) * 64 + b];
    r[tid] = s;
    __syncthreads();
    if (tid < 64)
        out[tid * NOUT + col] = r[tid] + r[64 + tid] + r[128 + tid] + r[192 + tid]
                              + b_ans[0];
}

extern "C" void kernel_launch(void* const* d_in, const int* in_sizes, int n_in,
                              void* d_out, int out_size, void* d_ws, size_t ws_size,
                              hipStream_t stream)
{
    const int*   prob  = (const int*)  d_in[0];
    const float* embed = (const float*)d_in[2];
    const float* w_ih  = (const float*)d_in[3];
    const float* w_hh  = (const float*)d_in[4];
    const float* b_ih  = (const float*)d_in[5];
    const float* b_hh  = (const float*)d_in[6];
    const float* w_ans = (const float*)d_in[7];
    const float* b_ans = (const float*)d_in[8];
    const float* h0    = (const float*)d_in[9];
    const float* c0    = (const float*)d_in[10];

    // ---- MFMA-path ws layout (bytes) ----
    char* W = (char*)d_ws;
    float*    cT_m  = (float*)   (W);              // 262,144 B
    float*    poutm = (float*)   (W + 262144);     // 4,063,232 B
    ushort_t* xf_hi = (ushort_t*)(W + 4325376);    // 8,323,072 B
    ushort_t* xf_lo = (ushort_t*)(W + 12648448);   // 8,323,072 B
    ushort_t* hf_hi = (ushort_t*)(W + 20971520);   // 16,777,216 B
    ushort_t* hf_lo = (ushort_t*)(W + 37748736);   // 16,777,216 B
    int*      bar_m = (int*)     (W + 54525952);   // 2,048 B

    const int DYN_LDS = 96 * 1024 + 12288;         // A-frags + redA(8K) + redB(4K)

    hipError_t err = hipFuncSetAttribute(
        (const void*)lstm_mfma,
        hipFuncAttributeMaxDynamicSharedMemorySize, DYN_LDS);

    if (err == hipSuccess) {
        hipMemsetAsync(bar_m, 0, 2048, stream);
        init_mfma<<<256, 256, 0, stream>>>(h0, c0, cT_m, hf_hi, hf_lo);
        embed_frag<<<NSTEP, 256, 0, stream>>>(prob, embed, xf_hi, xf_lo);

        void* args[] = {
            (void*)&xf_hi, (void*)&xf_lo, (void*)&hf_hi, (void*)&hf_lo,
            (void*)&cT_m, (void*)&w_ih, (void*)&w_hh, (void*)&b_ih,
            (void*)&b_hh, (void*)&w_ans, (void*)&poutm, (void*)&bar_m
        };
        err = hipLaunchCooperativeKernel((const void*)lstm_mfma,
                                         dim3(256), dim3(1024),
                                         args, DYN_LDS, stream);
        if (err == hipSuccess) {
            finalize_mfma<<<NOUT, 256, 0, stream>>>(poutm, b_ans, (float*)d_out);
            return;
        }
    }

    // ---- fallback: round-9 proven path (aliases the same ws region) ----
    float* ws     = (float*)d_ws;
    float* cT     = ws;                    // 65,536 fl
    float* pout   = ws + 65536;            // 2,031,616 fl
    float* xT     = ws + 2097152;          // 4,161,536 fl
    float* h_hist = ws + 6258688;          // 8,388,608 fl
    int*   bar    = (int*)(ws + 14647296);

    hipMemsetAsync(bar, 0, 2048, stream);
    init_state<<<256, 256, 0, stream>>>(h0, c0, h_hist, cT);
    embed_transpose<<<NSTEP, 256, 0, stream>>>(prob, embed, xT);

    void* args9[] = {
        (void*)&xT, (void*)&h_hist, (void*)&cT,
        (void*)&w_ih, (void*)&w_hh, (void*)&b_ih, (void*)&b_hh,
        (void*)&w_ans, (void*)&pout, (void*)&bar
    };
    hipLaunchCooperativeKernel((const void*)lstm_persist_hist,
                               dim3(NBLK), dim3(NTHR), args9, 0, stream);
    finalize_persist<<<NOUT, 256, 0, stream>>>(pout, b_ans, (float*)d_out);
}

// Round 5
// 858.325 us; speedup vs baseline: 2.0554x; 1.0080x over previous
//
#include <hip/hip_runtime.h>
#include <math.h>

#define BATCH   64
#define SEQLEN  128
#define EMBED   512
#define HID     1024
#define NSTEP   127
#define OUT0    65
#define NOUT    62

typedef unsigned short ushort_t;
typedef __attribute__((ext_vector_type(8))) __bf16 bf16x8;
typedef __attribute__((ext_vector_type(4))) float  f32x4;

__device__ __forceinline__ float sigmoidf_(float x) { return 1.f / (1.f + expf(-x)); }

__device__ __forceinline__ ushort_t f2bf(float f) {
    unsigned u = __builtin_bit_cast(unsigned, f);
    unsigned r = (u + 0x7FFFu + ((u >> 16) & 1u)) >> 16;   // round-to-nearest-even
    return (ushort_t)r;
}
__device__ __forceinline__ float bf2f(ushort_t s) {
    unsigned u = ((unsigned)s) << 16;
    return __builtin_bit_cast(float, u);
}

// ===================== MFMA path prep =====================

__global__ __launch_bounds__(256) void init_mfma(
    const float* __restrict__ h0, const float* __restrict__ c0,
    float* __restrict__ cT, ushort_t* __restrict__ hf_hi, ushort_t* __restrict__ hf_lo)
{
    int id = blockIdx.x * 256 + threadIdx.x;   // u*64+b
    int u = id >> 6, b = id & 63;
    cT[id] = c0[b * HID + u];
    float h = h0[b * HID + u];
    ushort_t hs = f2bf(h);
    ushort_t ls = f2bf(h - bf2f(hs));
    size_t idx = (((size_t)(u >> 5)) * 4 + (b >> 4)) * 512
               + ((((u & 31) >> 3) * 16) + (b & 15)) * 8 + (u & 7);
    hf_hi[idx] = hs;
    hf_lo[idx] = ls;
}

// coalesced — thread = (b, k-block-of-8); frag layout keeps k&7 contiguous so
// each thread writes two 16B bf16x8 stores.
__global__ __launch_bounds__(256) void embed_frag(
    const int* __restrict__ prob, const float* __restrict__ embed,
    ushort_t* __restrict__ xf_hi, ushort_t* __restrict__ xf_lo)
{
    int t = blockIdx.x;
    for (int e = threadIdx.x; e < 4096; e += 256) {
        int b  = e >> 6;         // 0..63
        int kb = e & 63;         // k-block of 8
        int k  = kb * 8;
        int tok = prob[b * SEQLEN + t];
        const float* row = embed + (size_t)tok * EMBED + k;
        float4 f0 = *(const float4*)(row);
        float4 f1 = *(const float4*)(row + 4);
        float fv[8] = { f0.x, f0.y, f0.z, f0.w, f1.x, f1.y, f1.z, f1.w };
        bf16x8 hv, lv;
        #pragma unroll
        for (int i = 0; i < 8; ++i) {
            ushort_t hs = f2bf(fv[i]);
            ushort_t ls = f2bf(fv[i] - bf2f(hs));
            hv[i] = __builtin_bit_cast(__bf16, hs);
            lv[i] = __builtin_bit_cast(__bf16, ls);
        }
        size_t idx = (((size_t)t * 16 + (kb >> 2)) * 4 + (b >> 4)) * 512
                   + (((kb & 3) * 16) + (b & 15)) * 8;
        *(bf16x8*)(xf_hi + idx) = hv;
        *(bf16x8*)(xf_lo + idx) = lv;
    }
}

// ===================== MFMA persistent kernel =====================
// 256 blocks x 1024 thr (1 block/CU, 16 waves = 48% occ). Block = 4 units =
// 16 gate-rows (MFMA M-tile). Wave w: N-tile wn=w&3, K-quarter kq=w>>2.
// Per-quarter arrival counters (r4, measured 865us total: block increments
// bar[(bid>>6)*32]; wave kq spins on bar[kq*32] >= 64*t).
// r5 change (ONLY delta vs the measured-865us kernel): ISSUE-ALL B loads.
// r4 counters (VGPR=56) prove the compiler kept the source's 1-deep prefetch:
// each h kstep serialized on a 200-900cy L2/L3 load latency (8 serial
// latencies/wave ~= 1-2.3us; TLP can't shorten a per-wave chain). Now all 16
// h loads (8 ks x hi/lo) and all 8 x loads are issued before their MFMA
// loops, collapsing 8 serial latencies into ~1 + throughput. Registers are
// free: 1024-thr blocks pin 4 waves/SIMD (<=512 VGPR/wave).
__global__ __launch_bounds__(1024) void lstm_mfma(
    const ushort_t* __restrict__ xf_hi, const ushort_t* __restrict__ xf_lo,
    ushort_t* __restrict__ hf_hi, ushort_t* __restrict__ hf_lo,
    const float* __restrict__ cT,
    const float* __restrict__ w_ih, const float* __restrict__ w_hh,
    const float* __restrict__ b_ih, const float* __restrict__ b_hh,
    const float* __restrict__ w_ans, float* __restrict__ pout,
    int* __restrict__ bar)
{
    extern __shared__ ushort_t smem[];
    ushort_t* a_hi = smem;                       // [ks 48][512] 48 KB
    ushort_t* a_lo = smem + 48 * 512;            // 48 KB
    float*    redA = (float*)(smem + 96 * 512);  // 8 KB (8 waves x 64 x f32x4)
    float*    redB = redA + 2048;                // 4 KB (4 waves x 64 x f32x4)

    const int tid = threadIdx.x;
    const int bid = blockIdx.x;
    const int w   = tid >> 6;        // 0..15
    const int wn  = w & 3;           // N-tile
    const int kq  = w >> 2;          // K-quarter 0..3
    const int L   = tid & 63;
    const int n   = L & 15;
    const int q   = L >> 4;
    const int u0  = bid * 4;
    const int ug  = u0 + q;
    const int bg  = wn * 16 + n;

    // per-quarter arrival counters, 128 B apart
    int* gc_me   = bar + kq * 32;            // wave's wait target
    int* gc_mine = bar + (bid >> 6) * 32;    // this block's arrival counter

    // ---- one-time: weight split -> A-frag LDS image ----
    for (int m = 0; m < 16; ++m) {
        int unit = m >> 2, gate = m & 3;
        size_t rowg = (size_t)gate * HID + u0 + unit;
        for (int k = tid; k < 1536; k += 1024) {
            float f = (k < EMBED) ? w_ih[rowg * EMBED + k]
                                  : w_hh[rowg * HID + (k - EMBED)];
            ushort_t hs = f2bf(f);
            ushort_t ls = f2bf(f - bf2f(hs));
            int off = (k >> 5) * 512 + (((k & 31) >> 3) * 16 + m) * 8 + (k & 7);
            a_hi[off] = hs;
            a_lo[off] = ls;
        }
    }

    float c = cT[ug * 64 + bg];
    float bs[4];
    #pragma unroll
    for (int j = 0; j < 4; ++j) bs[j] = b_ih[j * HID + ug] + b_hh[j * HID + ug];
    const float wansu = w_ans[ug];
    __syncthreads();

    for (int t = 0; t < NSTEP; ++t) {
        f32x4 acc = {0.f, 0.f, 0.f, 0.f};

        // ---- x phase: this wave's 4 ksteps (independent of h(t-1)) ----
        // issue-all: 8 global loads in flight, then MFMA.
        {
            const ushort_t* xh = xf_hi + (((size_t)t * 16 + kq * 4) * 4 + wn) * 512 + L * 8;
            const ushort_t* xl = xf_lo + (((size_t)t * 16 + kq * 4) * 4 + wn) * 512 + L * 8;
            bf16x8 bh[4], bl[4];
            #pragma unroll
            for (int ks = 0; ks < 4; ++ks) {
                bh[ks] = *(const bf16x8*)(xh + (size_t)ks * 2048);
                bl[ks] = *(const bf16x8*)(xl + (size_t)ks * 2048);
            }
            #pragma unroll
            for (int ks = 0; ks < 4; ++ks) {
                bf16x8 ah = *(const bf16x8*)(a_hi + (kq * 4 + ks) * 512 + L * 8);
                bf16x8 al = *(const bf16x8*)(a_lo + (kq * 4 + ks) * 512 + L * 8);
                acc = __builtin_amdgcn_mfma_f32_16x16x32_bf16(ah, bh[ks], acc, 0, 0, 0);
                acc = __builtin_amdgcn_mfma_f32_16x16x32_bf16(al, bh[ks], acc, 0, 0, 0);
                acc = __builtin_amdgcn_mfma_f32_16x16x32_bf16(ah, bl[ks], acc, 0, 0, 0);
            }
        }

        // ---- wait for THIS K-quarter of h(t): read-only spin (no cache inv) ----
        if (t > 0) {
            const int need = 64 * t;
            while (__hip_atomic_load(gc_me, __ATOMIC_RELAXED,
                                     __HIP_MEMORY_SCOPE_AGENT) < need)
                __builtin_amdgcn_s_sleep(1);
            __builtin_amdgcn_fence(__ATOMIC_ACQUIRE, "workgroup");
        }

        // ---- h phase: this wave's 8 ksteps, issue-all (16 loads in flight) ----
        {
            const ushort_t* hh = hf_hi + (((size_t)t * 32 + kq * 8) * 4 + wn) * 512 + L * 8;
            const ushort_t* hl = hf_lo + (((size_t)t * 32 + kq * 8) * 4 + wn) * 512 + L * 8;
            bf16x8 bh[8], bl[8];
            #pragma unroll
            for (int ks = 0; ks < 8; ++ks) {
                bh[ks] = *(const bf16x8*)(hh + (size_t)ks * 2048);
                bl[ks] = *(const bf16x8*)(hl + (size_t)ks * 2048);
            }
            #pragma unroll
            for (int ks = 0; ks < 8; ++ks) {
                bf16x8 ah = *(const bf16x8*)(a_hi + (16 + kq * 8 + ks) * 512 + L * 8);
                bf16x8 al = *(const bf16x8*)(a_lo + (16 + kq * 8 + ks) * 512 + L * 8);
                acc = __builtin_amdgcn_mfma_f32_16x16x32_bf16(ah, bh[ks], acc, 0, 0, 0);
                acc = __builtin_amdgcn_mfma_f32_16x16x32_bf16(al, bh[ks], acc, 0, 0, 0);
                acc = __builtin_amdgcn_mfma_f32_16x16x32_bf16(ah, bl[ks], acc, 0, 0, 0);
            }
        }

        // ---- K reduce: kq>=2 -> REDA; kq<2 add; kq1 -> REDB; kq0 adds ----
        if (kq >= 2)
            *(f32x4*)(redA + ((w - 8) * 64 + L) * 4) = acc;
        __syncthreads();
        if (kq < 2) {
            f32x4 r = *(const f32x4*)(redA + (w * 64 + L) * 4);  // (wn,kq) <- (wn,kq+2)
            acc += r;
        }
        if (kq == 1)
            *(f32x4*)(redB + ((w - 4) * 64 + L) * 4) = acc;
        __syncthreads();

        if (kq == 0) {
            f32x4 r = *(const f32x4*)(redB + (w * 64 + L) * 4);
            acc += r;

            // ---- finalize in-lane: lane owns (unit ug, batch bg) ----
            float ig = sigmoidf_(acc[0] + bs[0]);
            float fg = sigmoidf_(acc[1] + bs[1]);
            float gg = tanhf    (acc[2] + bs[2]);
            float og = sigmoidf_(acc[3] + bs[3]);
            c = fg * c + ig * gg;
            float h_new = og * tanhf(c);

            float p = h_new * wansu;
            p += __shfl_xor(p, 16, 64);
            p += __shfl_xor(p, 32, 64);
            if (t >= OUT0 && q == 0)
                pout[((size_t)(t - OUT0) * 256 + bid) * 64 + bg] = p;

            ushort_t hs = f2bf(h_new);
            ushort_t ls = f2bf(h_new - bf2f(hs));
            int kr = ug & 31, hks = ug >> 5;
            size_t idx = (((size_t)(t + 1) * 32 + hks) * 4 + wn) * 512
                       + (((kr >> 3) * 16) + n) * 8 + (kr & 7);
            __hip_atomic_store(&hf_hi[idx], hs, __ATOMIC_RELAXED,
                               __HIP_MEMORY_SCOPE_AGENT);
            __hip_atomic_store(&hf_lo[idx], ls, __ATOMIC_RELAXED,
                               __HIP_MEMORY_SCOPE_AGENT);
        }

        if (t == NSTEP - 1) break;

        __syncthreads();   // drains producer stores (vmcnt 0) before arrive
        if (tid == 0)
            __hip_atomic_fetch_add(gc_mine, 1, __ATOMIC_RELAXED,
                                   __HIP_MEMORY_SCOPE_AGENT);
    }
}

// out[b][col] = sum over 256 block partials + bias.
__global__ __launch_bounds__(256) void finalize_mfma(
    const float* __restrict__ pout, const float* __restrict__ b_ans,
    float* __restrict__ out)
{
    __shared__ float r[256];
    int col = blockIdx.x;
    int tid = threadIdx.x;
    int b = tid & 63, qq = tid >> 6;
    float s = 0.f;
    for (int i = qq; i < 256; i += 4)
        s += pout[((size_t)col * 256 + i) * 64 + b];
    r[tid] = s;
    __syncthreads();
    if (tid < 64)
        out[tid * NOUT + col] = r[tid] + r[64 + tid] + r[128 + tid] + r[192 + tid]
                              + b_ans[0];
}

// ===================== round-9 proven fallback path =====================
#define NBLK    512
#define NTHR    512
#define REDA_OFF 12288
#define REDB_OFF 14336
#define REDC_OFF 15360
#define C_OFF    15872
#define HEAD_OFF 16000
#define LDS_FLOATS 16128

__global__ __launch_bounds__(256) void init_state(
    const float* __restrict__ h0, const float* __restrict__ c0,
    float* __restrict__ hT, float* __restrict__ cT)
{
    int id = blockIdx.x * 256 + threadIdx.x;
    int u = id >> 6, b = id & 63;
    hT[id] = h0[b * HID + u];
    cT[id] = c0[b * HID + u];
}

__global__ __launch_bounds__(256) void embed_transpose(
    const int* __restrict__ prob, const float* __restrict__ embed,
    float* __restrict__ xT)
{
    __shared__ float xe[64 * 132];
    int t = blockIdx.x;
    int tid = threadIdx.x;
    for (int kt = 0; kt < 4; ++kt) {
        #pragma unroll
        for (int i = 0; i < 8; ++i) {
            int id = tid + i * 256;
            int b  = id >> 5;
            int k4 = id & 31;
            int tok = prob[b * SEQLEN + t];
            float4 v = *(const float4*)(embed + (size_t)tok * EMBED + kt * 128 + k4 * 4);
            *(float4*)(&xe[b * 132 + k4 * 4]) = v;
        }
        __syncthreads();
        #pragma unroll
        for (int i = 0; i < 8; ++i) {
            int id = tid + i * 256;
            int kl = id >> 4;
            int b4 = id & 15;
            float4 v;
            v.x = xe[(b4 * 4 + 0) * 132 + kl];
            v.y = xe[(b4 * 4 + 1) * 132 + kl];
            v.z = xe[(b4 * 4 + 2) * 132 + kl];
            v.w = xe[(b4 * 4 + 3) * 132 + kl];
            *(float4*)(&xT[((size_t)t * EMBED + kt * 128 + kl) * 64 + b4 * 4]) = v;
        }
        __syncthreads();
    }
}

__global__ __launch_bounds__(NTHR, 4) void lstm_persist_hist(
    const float* __restrict__ xT, float* __restrict__ h_hist,
    const float* __restrict__ cT,
    const float* __restrict__ w_ih, const float* __restrict__ w_hh,
    const float* __restrict__ b_ih, const float* __restrict__ b_hh,
    const float* __restrict__ w_ans, float* __restrict__ pout,
    int* __restrict__ bar)
{
    __shared__ float lds[LDS_FLOATS];
    const int tid = threadIdx.x;
    const int bid = blockIdx.x;
    const int b   = tid & 63;
    const int ksl = __builtin_amdgcn_readfirstlane(tid >> 6);
    const int u0  = bid * 2;

    int* sliceCnt = bar + (bid >> 6) * 32;
    int* mySlice  = bar + 256 + (bid >> 6) * 32;
    int* waitGo   = bar + 256 + ksl * 32;

    for (int idx = tid; idx < 12288; idx += NTHR) {
        int r  = idx / 1536;
        int k  = idx - r * 1536;
        int u2 = r & 1, gate = r >> 1;
        int row = gate * HID + u0 + u2;
        float v = (k < EMBED) ? w_ih[(size_t)row * EMBED + k]
                              : w_hh[(size_t)row * HID + (k - EMBED)];
        lds[(u2 * 1536 + k) * 4 + gate] = v;
    }
    if (tid < 128) lds[C_OFF + tid] = cT[u0 * 64 + tid];

    float bias[2][4], wans[2];
    #pragma unroll
    for (int uu = 0; uu < 2; ++uu) {
        #pragma unroll
        for (int j = 0; j < 4; ++j) {
            int rj = j * HID + u0 + uu;
            bias[uu][j] = b_ih[rj] + b_hh[rj];
        }
        wans[uu] = w_ans[u0 + uu];
    }
    __syncthreads();

    for (int t = 0; t < NSTEP; ++t) {
        const float* xt = xT + (size_t)t * EMBED * 64;
        const float* ht = h_hist + (size_t)t * HID * 64;
        float* hn_buf   = h_hist + (size_t)(t + 1) * HID * 64;

        float acc[2][4];
        #pragma unroll
        for (int uu = 0; uu < 2; ++uu)
            #pragma unroll
            for (int j = 0; j < 4; ++j) acc[uu][j] = 0.f;

        const int kx0 = ksl * 64;
        #pragma unroll 4
        for (int g = 0; g < 16; ++g) {
            const int k = kx0 + g * 4;
            float xv[4];
            #pragma unroll
            for (int i = 0; i < 4; ++i) xv[i] = xt[(size_t)(k + i) * 64 + b];
            #pragma unroll
            for (int i = 0; i < 4; ++i) {
                float4 wa = *(const float4*)&lds[(0 * 1536 + k + i) * 4];
                float4 wb = *(const float4*)&lds[(1 * 1536 + k + i) * 4];
                acc[0][0] = fmaf(wa.x, xv[i], acc[0][0]);
                acc[0][1] = fmaf(wa.y, xv[i], acc[0][1]);
                acc[0][2] = fmaf(wa.z, xv[i], acc[0][2]);
                acc[0][3] = fmaf(wa.w, xv[i], acc[0][3]);
                acc[1][0] = fmaf(wb.x, xv[i], acc[1][0]);
                acc[1][1] = fmaf(wb.y, xv[i], acc[1][1]);
                acc[1][2] = fmaf(wb.z, xv[i], acc[1][2]);
                acc[1][3] = fmaf(wb.w, xv[i], acc[1][3]);
            }
        }

        if (t > 0) {
            while (__hip_atomic_load(waitGo, __ATOMIC_RELAXED,
                                     __HIP_MEMORY_SCOPE_AGENT) < t)
                __builtin_amdgcn_s_sleep(4);
            __builtin_amdgcn_fence(__ATOMIC_ACQUIRE, "workgroup");
        }

        const int kh0 = ksl * 128;
        #pragma unroll 4
        for (int g = 0; g < 32; ++g) {
            const int kh = kh0 + g * 4;
            float hv[4];
            #pragma unroll
            for (int i = 0; i < 4; ++i)
                hv[i] = ht[(size_t)(kh + i) * 64 + b];
            #pragma unroll
            for (int i = 0; i < 4; ++i) {
                const int kw = EMBED + kh + i;
                float4 wa = *(const float4*)&lds[(0 * 1536 + kw) * 4];
                float4 wb = *(const float4*)&lds[(1 * 1536 + kw) * 4];
                acc[0][0] = fmaf(wa.x, hv[i], acc[0][0]);
                acc[0][1] = fmaf(wa.y, hv[i], acc[0][1]);
                acc[0][2] = fmaf(wa.z, hv[i], acc[0][2]);
                acc[0][3] = fmaf(wa.w, hv[i], acc[0][3]);
                acc[1][0] = fmaf(wb.x, hv[i], acc[1][0]);
                acc[1][1] = fmaf(wb.y, hv[i], acc[1][1]);
                acc[1][2] = fmaf(wb.z, hv[i], acc[1][2]);
                acc[1][3] = fmaf(wb.w, hv[i], acc[1][3]);
            }
        }

        if (ksl >= 4) {
            #pragma unroll
            for (int uu = 0; uu < 2; ++uu)
                #pragma unroll
                for (int j = 0; j < 4; ++j)
                    lds[REDA_OFF + (((ksl - 4) * 8) + uu * 4 + j) * 64 + b] = acc[uu][j];
        }
        __syncthreads();
        if (ksl < 4) {
            #pragma unroll
            for (int uu = 0; uu < 2; ++uu)
                #pragma unroll
                for (int j = 0; j < 4; ++j)
                    acc[uu][j] += lds[REDA_OFF + ((ksl * 8) + uu * 4 + j) * 64 + b];
        }
        if (ksl == 2 || ksl == 3) {
            #pragma unroll
            for (int uu = 0; uu < 2; ++uu)
                #pragma unroll
                for (int j = 0; j < 4; ++j)
                    lds[REDB_OFF + (((ksl - 2) * 8) + uu * 4 + j) * 64 + b] = acc[uu][j];
        }
        __syncthreads();
        if (ksl < 2) {
            #pragma unroll
            for (int uu = 0; uu < 2; ++uu)
                #pragma unroll
                for (int j = 0; j < 4; ++j)
                    acc[uu][j] += lds[REDB_OFF + ((ksl * 8) + uu * 4 + j) * 64 + b];
        }
        if (ksl == 0) {
            #pragma unroll
            for (int j = 0; j < 4; ++j)
                lds[REDC_OFF + j * 64 + b] = acc[1][j];
        }
        if (ksl == 1) {
            #pragma unroll
            for (int j = 0; j < 4; ++j)
                lds[REDC_OFF + (4 + j) * 64 + b] = acc[0][j];
        }
        __syncthreads();
        if (ksl < 2) {
            const int uu = ksl;
            float s[4];
            if (ksl == 0) {
                #pragma unroll
                for (int j = 0; j < 4; ++j)
                    s[j] = acc[0][j] + lds[REDC_OFF + (4 + j) * 64 + b];
            } else {
                #pragma unroll
                for (int j = 0; j < 4; ++j)
                    s[j] = acc[1][j] + lds[REDC_OFF + j * 64 + b];
            }
            float i_g = sigmoidf_(s[0] + bias[uu][0]);
            float f_g = sigmoidf_(s[1] + bias[uu][1]);
            float g_g = tanhf   (s[2] + bias[uu][2]);
            float o_g = sigmoidf_(s[3] + bias[uu][3]);
            float c_old = lds[C_OFF + uu * 64 + b];
            float c_new = f_g * c_old + i_g * g_g;
            float h_new = o_g * tanhf(c_new);
            lds[C_OFF + uu * 64 + b] = c_new;
            __hip_atomic_store(&hn_buf[(u0 + uu) * 64 + b], h_new,
                               __ATOMIC_RELAXED, __HIP_MEMORY_SCOPE_AGENT);
            lds[HEAD_OFF + uu * 64 + b] = h_new * wans[uu];
        }

        __syncthreads();
        if (t >= OUT0 && tid < 64) {
            pout[((size_t)(t - OUT0) * NBLK + bid) * 64 + tid] =
                lds[HEAD_OFF + tid] + lds[HEAD_OFF + 64 + tid];
        }
        if (t == NSTEP - 1) break;
        if (tid == 0) {
            int r = __hip_atomic_fetch_add(sliceCnt, 1, __ATOMIC_RELAXED,
                                           __HIP_MEMORY_SCOPE_AGENT);
            if (r == 64 * (t + 1) - 1)
                __hip_atomic_store(mySlice, t + 1, __ATOMIC_RELAXED,
                                   __HIP_MEMORY_SCOPE_AGENT);
        }
    }
}

__global__ __launch_bounds__(256) void finalize_persist(
    const float* __restrict__ pout, const float* __restrict__ b_ans,
    float* __restrict__ out)
{
    __shared__ float r[256];
    int col = blockIdx.x;
    int tid = threadIdx.x;
    int b = tid & 63, qq = tid >> 6;
    float s = 0.f;
    for (int i = qq; i < NBLK; i += 4)
        s += pout[((size_t)col * NBLK + i) * 64 + b];
    r[tid] = s;
    __syncthreads();
    if (tid < 64)
        out[tid * NOUT + col] = r[tid] + r[64 + tid] + r[128 + tid] + r[192 + tid]
                              + b_ans[0];
}

extern "C" void kernel_launch(void* const* d_in, const int* in_sizes, int n_in,
                              void* d_out, int out_size, void* d_ws, size_t ws_size,
                              hipStream_t stream)
{
    const int*   prob  = (const int*)  d_in[0];
    const float* embed = (const float*)d_in[2];
    const float* w_ih  = (const float*)d_in[3];
    const float* w_hh  = (const float*)d_in[4];
    const float* b_ih  = (const float*)d_in[5];
    const float* b_hh  = (const float*)d_in[6];
    const float* w_ans = (const float*)d_in[7];
    const float* b_ans = (const float*)d_in[8];
    const float* h0    = (const float*)d_in[9];
    const float* c0    = (const float*)d_in[10];

    // ---- MFMA-path ws layout (bytes) ----
    char* W = (char*)d_ws;
    float*    cT_m  = (float*)   (W);              // 262,144 B
    float*    poutm = (float*)   (W + 262144);     // 4,063,232 B
    ushort_t* xf_hi = (ushort_t*)(W + 4325376);    // 8,323,072 B
    ushort_t* xf_lo = (ushort_t*)(W + 12648448);   // 8,323,072 B
    ushort_t* hf_hi = (ushort_t*)(W + 20971520);   // 16,777,216 B
    ushort_t* hf_lo = (ushort_t*)(W + 37748736);   // 16,777,216 B
    int*      bar_m = (int*)     (W + 54525952);   // 2,048 B

    const int DYN_LDS = 96 * 1024 + 12288;         // A-frags + redA(8K) + redB(4K)

    hipError_t err = hipFuncSetAttribute(
        (const void*)lstm_mfma,
        hipFuncAttributeMaxDynamicSharedMemorySize, DYN_LDS);

    if (err == hipSuccess) {
        hipMemsetAsync(bar_m, 0, 2048, stream);
        init_mfma<<<256, 256, 0, stream>>>(h0, c0, cT_m, hf_hi, hf_lo);
        embed_frag<<<NSTEP, 256, 0, stream>>>(prob, embed, xf_hi, xf_lo);

        void* args[] = {
            (void*)&xf_hi, (void*)&xf_lo, (void*)&hf_hi, (void*)&hf_lo,
            (void*)&cT_m, (void*)&w_ih, (void*)&w_hh, (void*)&b_ih,
            (void*)&b_hh, (void*)&w_ans, (void*)&poutm, (void*)&bar_m
        };
        err = hipLaunchCooperativeKernel((const void*)lstm_mfma,
                                         dim3(256), dim3(1024),
                                         args, DYN_LDS, stream);
        if (err == hipSuccess) {
            finalize_mfma<<<NOUT, 256, 0, stream>>>(poutm, b_ans, (float*)d_out);
            return;
        }
    }

    // ---- fallback: round-9 proven path (aliases the same ws region) ----
    float* ws     = (float*)d_ws;
    float* cT     = ws;                    // 65,536 fl
    float* pout   = ws + 65536;            // 2,031,616 fl
    float* xT     = ws + 2097152;          // 4,161,536 fl
    float* h_hist = ws + 6258688;          // 8,388,608 fl
    int*   bar    = (int*)(ws + 14647296);

    hipMemsetAsync(bar, 0, 2048, stream);
    init_state<<<256, 256, 0, stream>>>(h0, c0, h_hist, cT);
    embed_transpose<<<NSTEP, 256, 0, stream>>>(prob, embed, xT);

    void* args9[] = {
        (void*)&xT, (void*)&h_hist, (void*)&cT,
        (void*)&w_ih, (void*)&w_hh, (void*)&b_ih, (void*)&b_hh,
        (void*)&w_ans, (void*)&pout, (void*)&bar
    };
    hipLaunchCooperativeKernel((const void*)lstm_persist_hist,
                               dim3(NBLK), dim3(NTHR), args9, 0, stream);
    finalize_persist<<<NOUT, 256, 0, stream>>>(pout, b_ans, (float*)d_out);
}

// Round 6
// 804.070 us; speedup vs baseline: 2.1941x; 1.0675x over previous
//
#include <hip/hip_runtime.h>
#include <math.h>

#define BATCH   64
#define SEQLEN  128
#define EMBED   512
#define HID     1024
#define NSTEP   127
#define OUT0    65
#define NOUT    62

typedef unsigned short ushort_t;
typedef __attribute__((ext_vector_type(8))) __bf16 bf16x8;
typedef __attribute__((ext_vector_type(4))) float  f32x4;

__device__ __forceinline__ float sigmoidf_(float x) { return 1.f / (1.f + expf(-x)); }

__device__ __forceinline__ ushort_t f2bf(float f) {
    unsigned u = __builtin_bit_cast(unsigned, f);
    unsigned r = (u + 0x7FFFu + ((u >> 16) & 1u)) >> 16;   // round-to-nearest-even
    return (ushort_t)r;
}
__device__ __forceinline__ float bf2f(ushort_t s) {
    unsigned u = ((unsigned)s) << 16;
    return __builtin_bit_cast(float, u);
}

// ===================== MFMA path prep =====================

__global__ __launch_bounds__(256) void init_mfma(
    const float* __restrict__ h0, const float* __restrict__ c0,
    float* __restrict__ cT, ushort_t* __restrict__ hf_hi, ushort_t* __restrict__ hf_lo)
{
    int id = blockIdx.x * 256 + threadIdx.x;   // u*64+b
    int u = id >> 6, b = id & 63;
    cT[id] = c0[b * HID + u];
    float h = h0[b * HID + u];
    ushort_t hs = f2bf(h);
    ushort_t ls = f2bf(h - bf2f(hs));
    size_t idx = (((size_t)(u >> 5)) * 4 + (b >> 4)) * 512
               + ((((u & 31) >> 3) * 16) + (b & 15)) * 8 + (u & 7);
    hf_hi[idx] = hs;
    hf_lo[idx] = ls;
}

// coalesced — thread = (b, k-block-of-8); frag layout keeps k&7 contiguous so
// each thread writes two 16B bf16x8 stores.
__global__ __launch_bounds__(256) void embed_frag(
    const int* __restrict__ prob, const float* __restrict__ embed,
    ushort_t* __restrict__ xf_hi, ushort_t* __restrict__ xf_lo)
{
    int t = blockIdx.x;
    for (int e = threadIdx.x; e < 4096; e += 256) {
        int b  = e >> 6;         // 0..63
        int kb = e & 63;         // k-block of 8
        int k  = kb * 8;
        int tok = prob[b * SEQLEN + t];
        const float* row = embed + (size_t)tok * EMBED + k;
        float4 f0 = *(const float4*)(row);
        float4 f1 = *(const float4*)(row + 4);
        float fv[8] = { f0.x, f0.y, f0.z, f0.w, f1.x, f1.y, f1.z, f1.w };
        bf16x8 hv, lv;
        #pragma unroll
        for (int i = 0; i < 8; ++i) {
            ushort_t hs = f2bf(fv[i]);
            ushort_t ls = f2bf(fv[i] - bf2f(hs));
            hv[i] = __builtin_bit_cast(__bf16, hs);
            lv[i] = __builtin_bit_cast(__bf16, ls);
        }
        size_t idx = (((size_t)t * 16 + (kb >> 2)) * 4 + (b >> 4)) * 512
                   + (((kb & 3) * 16) + (b & 15)) * 8;
        *(bf16x8*)(xf_hi + idx) = hv;
        *(bf16x8*)(xf_lo + idx) = lv;
    }
}

// ===================== MFMA persistent kernel =====================
// 256 blocks x 1024 thr (1 block/CU, 16 waves = 48% occ). Block = 4 units =
// 16 gate-rows (MFMA M-tile). Wave w: N-tile wn=w&3, K-quarter kq=w>>2.
// Per-quarter arrival counters (r4, measured 865us total).
// r6 change (ONLY delta vs the measured-858us r5 kernel): the issue-all B
// loads are now FORCED with sched_group_barrier. r5's counters (VGPR=56,
// identical dur) proved the scheduler sank the source-level issue-all back
// to 1-deep to minimize register pressure; SGB is a hard constraint it must
// satisfy: cluster all VMEM_READs of a phase first, then (DS_READ x2,
// MFMA x3) per kstep. Masks per T19: VMEM_READ=0x20 DS_READ=0x100 MFMA=0x8.
// B-register peak = 64 VGPR (16 x bf16x8); total ~115-125 < 128/wave cap.
__global__ __launch_bounds__(1024) void lstm_mfma(
    const ushort_t* __restrict__ xf_hi, const ushort_t* __restrict__ xf_lo,
    ushort_t* __restrict__ hf_hi, ushort_t* __restrict__ hf_lo,
    const float* __restrict__ cT,
    const float* __restrict__ w_ih, const float* __restrict__ w_hh,
    const float* __restrict__ b_ih, const float* __restrict__ b_hh,
    const float* __restrict__ w_ans, float* __restrict__ pout,
    int* __restrict__ bar)
{
    extern __shared__ ushort_t smem[];
    ushort_t* a_hi = smem;                       // [ks 48][512] 48 KB
    ushort_t* a_lo = smem + 48 * 512;            // 48 KB
    float*    redA = (float*)(smem + 96 * 512);  // 8 KB (8 waves x 64 x f32x4)
    float*    redB = redA + 2048;                // 4 KB (4 waves x 64 x f32x4)

    const int tid = threadIdx.x;
    const int bid = blockIdx.x;
    const int w   = tid >> 6;        // 0..15
    const int wn  = w & 3;           // N-tile
    const int kq  = w >> 2;          // K-quarter 0..3
    const int L   = tid & 63;
    const int n   = L & 15;
    const int q   = L >> 4;
    const int u0  = bid * 4;
    const int ug  = u0 + q;
    const int bg  = wn * 16 + n;

    // per-quarter arrival counters, 128 B apart
    int* gc_me   = bar + kq * 32;            // wave's wait target
    int* gc_mine = bar + (bid >> 6) * 32;    // this block's arrival counter

    // ---- one-time: weight split -> A-frag LDS image ----
    for (int m = 0; m < 16; ++m) {
        int unit = m >> 2, gate = m & 3;
        size_t rowg = (size_t)gate * HID + u0 + unit;
        for (int k = tid; k < 1536; k += 1024) {
            float f = (k < EMBED) ? w_ih[rowg * EMBED + k]
                                  : w_hh[rowg * HID + (k - EMBED)];
            ushort_t hs = f2bf(f);
            ushort_t ls = f2bf(f - bf2f(hs));
            int off = (k >> 5) * 512 + (((k & 31) >> 3) * 16 + m) * 8 + (k & 7);
            a_hi[off] = hs;
            a_lo[off] = ls;
        }
    }

    float c = cT[ug * 64 + bg];
    float bs[4];
    #pragma unroll
    for (int j = 0; j < 4; ++j) bs[j] = b_ih[j * HID + ug] + b_hh[j * HID + ug];
    const float wansu = w_ans[ug];
    __syncthreads();

    for (int t = 0; t < NSTEP; ++t) {
        f32x4 acc = {0.f, 0.f, 0.f, 0.f};

        // ---- x phase: this wave's 4 ksteps (independent of h(t-1)) ----
        // issue-all: 8 global loads in flight, then MFMA; SGB-enforced.
        {
            const ushort_t* xh = xf_hi + (((size_t)t * 16 + kq * 4) * 4 + wn) * 512 + L * 8;
            const ushort_t* xl = xf_lo + (((size_t)t * 16 + kq * 4) * 4 + wn) * 512 + L * 8;
            bf16x8 bh[4], bl[4];
            #pragma unroll
            for (int ks = 0; ks < 4; ++ks) {
                bh[ks] = *(const bf16x8*)(xh + (size_t)ks * 2048);
                bl[ks] = *(const bf16x8*)(xl + (size_t)ks * 2048);
            }
            #pragma unroll
            for (int ks = 0; ks < 4; ++ks) {
                bf16x8 ah = *(const bf16x8*)(a_hi + (kq * 4 + ks) * 512 + L * 8);
                bf16x8 al = *(const bf16x8*)(a_lo + (kq * 4 + ks) * 512 + L * 8);
                acc = __builtin_amdgcn_mfma_f32_16x16x32_bf16(ah, bh[ks], acc, 0, 0, 0);
                acc = __builtin_amdgcn_mfma_f32_16x16x32_bf16(al, bh[ks], acc, 0, 0, 0);
                acc = __builtin_amdgcn_mfma_f32_16x16x32_bf16(ah, bl[ks], acc, 0, 0, 0);
            }
            // schedule template: 8 VMEM_READ, then per-ks {2 DS_READ, 3 MFMA}
            __builtin_amdgcn_sched_group_barrier(0x020, 8, 0);
            #pragma unroll
            for (int ks = 0; ks < 4; ++ks) {
                __builtin_amdgcn_sched_group_barrier(0x100, 2, 0);
                __builtin_amdgcn_sched_group_barrier(0x008, 3, 0);
            }
        }

        // ---- wait for THIS K-quarter of h(t): read-only spin (no cache inv) ----
        if (t > 0) {
            const int need = 64 * t;
            while (__hip_atomic_load(gc_me, __ATOMIC_RELAXED,
                                     __HIP_MEMORY_SCOPE_AGENT) < need)
                __builtin_amdgcn_s_sleep(1);
            __builtin_amdgcn_fence(__ATOMIC_ACQUIRE, "workgroup");
        }

        // ---- h phase: this wave's 8 ksteps, issue-all (16 loads in flight),
        // SGB-enforced ----
        {
            const ushort_t* hh = hf_hi + (((size_t)t * 32 + kq * 8) * 4 + wn) * 512 + L * 8;
            const ushort_t* hl = hf_lo + (((size_t)t * 32 + kq * 8) * 4 + wn) * 512 + L * 8;
            bf16x8 bh[8], bl[8];
            #pragma unroll
            for (int ks = 0; ks < 8; ++ks) {
                bh[ks] = *(const bf16x8*)(hh + (size_t)ks * 2048);
                bl[ks] = *(const bf16x8*)(hl + (size_t)ks * 2048);
            }
            #pragma unroll
            for (int ks = 0; ks < 8; ++ks) {
                bf16x8 ah = *(const bf16x8*)(a_hi + (16 + kq * 8 + ks) * 512 + L * 8);
                bf16x8 al = *(const bf16x8*)(a_lo + (16 + kq * 8 + ks) * 512 + L * 8);
                acc = __builtin_amdgcn_mfma_f32_16x16x32_bf16(ah, bh[ks], acc, 0, 0, 0);
                acc = __builtin_amdgcn_mfma_f32_16x16x32_bf16(al, bh[ks], acc, 0, 0, 0);
                acc = __builtin_amdgcn_mfma_f32_16x16x32_bf16(ah, bl[ks], acc, 0, 0, 0);
            }
            // schedule template: 16 VMEM_READ, then per-ks {2 DS_READ, 3 MFMA}
            __builtin_amdgcn_sched_group_barrier(0x020, 16, 0);
            #pragma unroll
            for (int ks = 0; ks < 8; ++ks) {
                __builtin_amdgcn_sched_group_barrier(0x100, 2, 0);
                __builtin_amdgcn_sched_group_barrier(0x008, 3, 0);
            }
        }

        // ---- K reduce: kq>=2 -> REDA; kq<2 add; kq1 -> REDB; kq0 adds ----
        if (kq >= 2)
            *(f32x4*)(redA + ((w - 8) * 64 + L) * 4) = acc;
        __syncthreads();
        if (kq < 2) {
            f32x4 r = *(const f32x4*)(redA + (w * 64 + L) * 4);  // (wn,kq) <- (wn,kq+2)
            acc += r;
        }
        if (kq == 1)
            *(f32x4*)(redB + ((w - 4) * 64 + L) * 4) = acc;
        __syncthreads();

        if (kq == 0) {
            f32x4 r = *(const f32x4*)(redB + (w * 64 + L) * 4);
            acc += r;

            // ---- finalize in-lane: lane owns (unit ug, batch bg) ----
            float ig = sigmoidf_(acc[0] + bs[0]);
            float fg = sigmoidf_(acc[1] + bs[1]);
            float gg = tanhf    (acc[2] + bs[2]);
            float og = sigmoidf_(acc[3] + bs[3]);
            c = fg * c + ig * gg;
            float h_new = og * tanhf(c);

            float p = h_new * wansu;
            p += __shfl_xor(p, 16, 64);
            p += __shfl_xor(p, 32, 64);
            if (t >= OUT0 && q == 0)
                pout[((size_t)(t - OUT0) * 256 + bid) * 64 + bg] = p;

            ushort_t hs = f2bf(h_new);
            ushort_t ls = f2bf(h_new - bf2f(hs));
            int kr = ug & 31, hks = ug >> 5;
            size_t idx = (((size_t)(t + 1) * 32 + hks) * 4 + wn) * 512
                       + (((kr >> 3) * 16) + n) * 8 + (kr & 7);
            __hip_atomic_store(&hf_hi[idx], hs, __ATOMIC_RELAXED,
                               __HIP_MEMORY_SCOPE_AGENT);
            __hip_atomic_store(&hf_lo[idx], ls, __ATOMIC_RELAXED,
                               __HIP_MEMORY_SCOPE_AGENT);
        }

        if (t == NSTEP - 1) break;

        __syncthreads();   // drains producer stores (vmcnt 0) before arrive
        if (tid == 0)
            __hip_atomic_fetch_add(gc_mine, 1, __ATOMIC_RELAXED,
                                   __HIP_MEMORY_SCOPE_AGENT);
    }
}

// out[b][col] = sum over 256 block partials + bias.
__global__ __launch_bounds__(256) void finalize_mfma(
    const float* __restrict__ pout, const float* __restrict__ b_ans,
    float* __restrict__ out)
{
    __shared__ float r[256];
    int col = blockIdx.x;
    int tid = threadIdx.x;
    int b = tid & 63, qq = tid >> 6;
    float s = 0.f;
    for (int i = qq; i < 256; i += 4)
        s += pout[((size_t)col * 256 + i) * 64 + b];
    r[tid] = s;
    __syncthreads();
    if (tid < 64)
        out[tid * NOUT + col] = r[tid] + r[64 + tid] + r[128 + tid] + r[192 + tid]
                              + b_ans[0];
}

// ===================== round-9 proven fallback path =====================
#define NBLK    512
#define NTHR    512
#define REDA_OFF 12288
#define REDB_OFF 14336
#define REDC_OFF 15360
#define C_OFF    15872
#define HEAD_OFF 16000
#define LDS_FLOATS 16128

__global__ __launch_bounds__(256) void init_state(
    const float* __restrict__ h0, const float* __restrict__ c0,
    float* __restrict__ hT, float* __restrict__ cT)
{
    int id = blockIdx.x * 256 + threadIdx.x;
    int u = id >> 6, b = id & 63;
    hT[id] = h0[b * HID + u];
    cT[id] = c0[b * HID + u];
}

__global__ __launch_bounds__(256) void embed_transpose(
    const int* __restrict__ prob, const float* __restrict__ embed,
    float* __restrict__ xT)
{
    __shared__ float xe[64 * 132];
    int t = blockIdx.x;
    int tid = threadIdx.x;
    for (int kt = 0; kt < 4; ++kt) {
        #pragma unroll
        for (int i = 0; i < 8; ++i) {
            int id = tid + i * 256;
            int b  = id >> 5;
            int k4 = id & 31;
            int tok = prob[b * SEQLEN + t];
            float4 v = *(const float4*)(embed + (size_t)tok * EMBED + kt * 128 + k4 * 4);
            *(float4*)(&xe[b * 132 + k4 * 4]) = v;
        }
        __syncthreads();
        #pragma unroll
        for (int i = 0; i < 8; ++i) {
            int id = tid + i * 256;
            int kl = id >> 4;
            int b4 = id & 15;
            float4 v;
            v.x = xe[(b4 * 4 + 0) * 132 + kl];
            v.y = xe[(b4 * 4 + 1) * 132 + kl];
            v.z = xe[(b4 * 4 + 2) * 132 + kl];
            v.w = xe[(b4 * 4 + 3) * 132 + kl];
            *(float4*)(&xT[((size_t)t * EMBED + kt * 128 + kl) * 64 + b4 * 4]) = v;
        }
        __syncthreads();
    }
}

__global__ __launch_bounds__(NTHR, 4) void lstm_persist_hist(
    const float* __restrict__ xT, float* __restrict__ h_hist,
    const float* __restrict__ cT,
    const float* __restrict__ w_ih, const float* __restrict__ w_hh,
    const float* __restrict__ b_ih, const float* __restrict__ b_hh,
    const float* __restrict__ w_ans, float* __restrict__ pout,
    int* __restrict__ bar)
{
    __shared__ float lds[LDS_FLOATS];
    const int tid = threadIdx.x;
    const int bid = blockIdx.x;
    const int b   = tid & 63;
    const int ksl = __builtin_amdgcn_readfirstlane(tid >> 6);
    const int u0  = bid * 2;

    int* sliceCnt = bar + (bid >> 6) * 32;
    int* mySlice  = bar + 256 + (bid >> 6) * 32;
    int* waitGo   = bar + 256 + ksl * 32;

    for (int idx = tid; idx < 12288; idx += NTHR) {
        int r  = idx / 1536;
        int k  = idx - r * 1536;
        int u2 = r & 1, gate = r >> 1;
        int row = gate * HID + u0 + u2;
        float v = (k < EMBED) ? w_ih[(size_t)row * EMBED + k]
                              : w_hh[(size_t)row * HID + (k - EMBED)];
        lds[(u2 * 1536 + k) * 4 + gate] = v;
    }
    if (tid < 128) lds[C_OFF + tid] = cT[u0 * 64 + tid];

    float bias[2][4], wans[2];
    #pragma unroll
    for (int uu = 0; uu < 2; ++uu) {
        #pragma unroll
        for (int j = 0; j < 4; ++j) {
            int rj = j * HID + u0 + uu;
            bias[uu][j] = b_ih[rj] + b_hh[rj];
        }
        wans[uu] = w_ans[u0 + uu];
    }
    __syncthreads();

    for (int t = 0; t < NSTEP; ++t) {
        const float* xt = xT + (size_t)t * EMBED * 64;
        const float* ht = h_hist + (size_t)t * HID * 64;
        float* hn_buf   = h_hist + (size_t)(t + 1) * HID * 64;

        float acc[2][4];
        #pragma unroll
        for (int uu = 0; uu < 2; ++uu)
            #pragma unroll
            for (int j = 0; j < 4; ++j) acc[uu][j] = 0.f;

        const int kx0 = ksl * 64;
        #pragma unroll 4
        for (int g = 0; g < 16; ++g) {
            const int k = kx0 + g * 4;
            float xv[4];
            #pragma unroll
            for (int i = 0; i < 4; ++i) xv[i] = xt[(size_t)(k + i) * 64 + b];
            #pragma unroll
            for (int i = 0; i < 4; ++i) {
                float4 wa = *(const float4*)&lds[(0 * 1536 + k + i) * 4];
                float4 wb = *(const float4*)&lds[(1 * 1536 + k + i) * 4];
                acc[0][0] = fmaf(wa.x, xv[i], acc[0][0]);
                acc[0][1] = fmaf(wa.y, xv[i], acc[0][1]);
                acc[0][2] = fmaf(wa.z, xv[i], acc[0][2]);
                acc[0][3] = fmaf(wa.w, xv[i], acc[0][3]);
                acc[1][0] = fmaf(wb.x, xv[i], acc[1][0]);
                acc[1][1] = fmaf(wb.y, xv[i], acc[1][1]);
                acc[1][2] = fmaf(wb.z, xv[i], acc[1][2]);
                acc[1][3] = fmaf(wb.w, xv[i], acc[1][3]);
            }
        }

        if (t > 0) {
            while (__hip_atomic_load(waitGo, __ATOMIC_RELAXED,
                                     __HIP_MEMORY_SCOPE_AGENT) < t)
                __builtin_amdgcn_s_sleep(4);
            __builtin_amdgcn_fence(__ATOMIC_ACQUIRE, "workgroup");
        }

        const int kh0 = ksl * 128;
        #pragma unroll 4
        for (int g = 0; g < 32; ++g) {
            const int kh = kh0 + g * 4;
            float hv[4];
            #pragma unroll
            for (int i = 0; i < 4; ++i)
                hv[i] = ht[(size_t)(kh + i) * 64 + b];
            #pragma unroll
            for (int i = 0; i < 4; ++i) {
                const int kw = EMBED + kh + i;
                float4 wa = *(const float4*)&lds[(0 * 1536 + kw) * 4];
                float4 wb = *(const float4*)&lds[(1 * 1536 + kw) * 4];
                acc[0][0] = fmaf(wa.x, hv[i], acc[0][0]);
                acc[0][1] = fmaf(wa.y, hv[i], acc[0][1]);
                acc[0][2] = fmaf(wa.z, hv[i], acc[0][2]);
                acc[0][3] = fmaf(wa.w, hv[i], acc[0][3]);
                acc[1][0] = fmaf(wb.x, hv[i], acc[1][0]);
                acc[1][1] = fmaf(wb.y, hv[i], acc[1][1]);
                acc[1][2] = fmaf(wb.z, hv[i], acc[1][2]);
                acc[1][3] = fmaf(wb.w, hv[i], acc[1][3]);
            }
        }

        if (ksl >= 4) {
            #pragma unroll
            for (int uu = 0; uu < 2; ++uu)
                #pragma unroll
                for (int j = 0; j < 4; ++j)
                    lds[REDA_OFF + (((ksl - 4) * 8) + uu * 4 + j) * 64 + b] = acc[uu][j];
        }
        __syncthreads();
        if (ksl < 4) {
            #pragma unroll
            for (int uu = 0; uu < 2; ++uu)
                #pragma unroll
                for (int j = 0; j < 4; ++j)
                    acc[uu][j] += lds[REDA_OFF + ((ksl * 8) + uu * 4 + j) * 64 + b];
        }
        if (ksl == 2 || ksl == 3) {
            #pragma unroll
            for (int uu = 0; uu < 2; ++uu)
                #pragma unroll
                for (int j = 0; j < 4; ++j)
                    lds[REDB_OFF + (((ksl - 2) * 8) + uu * 4 + j) * 64 + b] = acc[uu][j];
        }
        __syncthreads();
        if (ksl < 2) {
            #pragma unroll
            for (int uu = 0; uu < 2; ++uu)
                #pragma unroll
                for (int j = 0; j < 4; ++j)
                    acc[uu][j] += lds[REDB_OFF + ((ksl * 8) + uu * 4 + j) * 64 + b];
        }
        if (ksl == 0) {
            #pragma unroll
            for (int j = 0; j < 4; ++j)
                lds[REDC_OFF + j * 64 + b] = acc[1][j];
        }
        if (ksl == 1) {
            #pragma unroll
            for (int j = 0; j < 4; ++j)
                lds[REDC_OFF + (4 + j) * 64 + b] = acc[0][j];
        }
        __syncthreads();
        if (ksl < 2) {
            const int uu = ksl;
            float s[4];
            if (ksl == 0) {
                #pragma unroll
                for (int j = 0; j < 4; ++j)
                    s[j] = acc[0][j] + lds[REDC_OFF + (4 + j) * 64 + b];
            } else {
                #pragma unroll
                for (int j = 0; j < 4; ++j)
                    s[j] = acc[1][j] + lds[REDC_OFF + j * 64 + b];
            }
            float i_g = sigmoidf_(s[0] + bias[uu][0]);
            float f_g = sigmoidf_(s[1] + bias[uu][1]);
            float g_g = tanhf   (s[2] + bias[uu][2]);
            float o_g = sigmoidf_(s[3] + bias[uu][3]);
            float c_old = lds[C_OFF + uu * 64 + b];
            float c_new = f_g * c_old + i_g * g_g;
            float h_new = o_g * tanhf(c_new);
            lds[C_OFF + uu * 64 + b] = c_new;
            __hip_atomic_store(&hn_buf[(u0 + uu) * 64 + b], h_new,
                               __ATOMIC_RELAXED, __HIP_MEMORY_SCOPE_AGENT);
            lds[HEAD_OFF + uu * 64 + b] = h_new * wans[uu];
        }

        __syncthreads();
        if (t >= OUT0 && tid < 64) {
            pout[((size_t)(t - OUT0) * NBLK + bid) * 64 + tid] =
                lds[HEAD_OFF + tid] + lds[HEAD_OFF + 64 + tid];
        }
        if (t == NSTEP - 1) break;
        if (tid == 0) {
            int r = __hip_atomic_fetch_add(sliceCnt, 1, __ATOMIC_RELAXED,
                                           __HIP_MEMORY_SCOPE_AGENT);
            if (r == 64 * (t + 1) - 1)
                __hip_atomic_store(mySlice, t + 1, __ATOMIC_RELAXED,
                                   __HIP_MEMORY_SCOPE_AGENT);
        }
    }
}

__global__ __launch_bounds__(256) void finalize_persist(
    const float* __restrict__ pout, const float* __restrict__ b_ans,
    float* __restrict__ out)
{
    __shared__ float r[256];
    int col = blockIdx.x;
    int tid = threadIdx.x;
    int b = tid & 63, qq = tid >> 6;
    float s = 0.f;
    for (int i = qq; i < NBLK; i += 4)
        s += pout[((size_t)col * NBLK + i) * 64 + b];
    r[tid] = s;
    __syncthreads();
    if (tid < 64)
        out[tid * NOUT + col] = r[tid] + r[64 + tid] + r[128 + tid] + r[192 + tid]
                              + b_ans[0];
}

extern "C" void kernel_launch(void* const* d_in, const int* in_sizes, int n_in,
                              void* d_out, int out_size, void* d_ws, size_t ws_size,
                              hipStream_t stream)
{
    const int*   prob  = (const int*)  d_in[0];
    const float* embed = (const float*)d_in[2];
    const float* w_ih  = (const float*)d_in[3];
    const float* w_hh  = (const float*)d_in[4];
    const float* b_ih  = (const float*)d_in[5];
    const float* b_hh  = (const float*)d_in[6];
    const float* w_ans = (const float*)d_in[7];
    const float* b_ans = (const float*)d_in[8];
    const float* h0    = (const float*)d_in[9];
    const float* c0    = (const float*)d_in[10];

    // ---- MFMA-path ws layout (bytes) ----
    char* W = (char*)d_ws;
    float*    cT_m  = (float*)   (W);              // 262,144 B
    float*    poutm = (float*)   (W + 262144);     // 4,063,232 B
    ushort_t* xf_hi = (ushort_t*)(W + 4325376);    // 8,323,072 B
    ushort_t* xf_lo = (ushort_t*)(W + 12648448);   // 8,323,072 B
    ushort_t* hf_hi = (ushort_t*)(W + 20971520);   // 16,777,216 B
    ushort_t* hf_lo = (ushort_t*)(W + 37748736);   // 16,777,216 B
    int*      bar_m = (int*)     (W + 54525952);   // 2,048 B

    const int DYN_LDS = 96 * 1024 + 12288;         // A-frags + redA(8K) + redB(4K)

    hipError_t err = hipFuncSetAttribute(
        (const void*)lstm_mfma,
        hipFuncAttributeMaxDynamicSharedMemorySize, DYN_LDS);

    if (err == hipSuccess) {
        hipMemsetAsync(bar_m, 0, 2048, stream);
        init_mfma<<<256, 256, 0, stream>>>(h0, c0, cT_m, hf_hi, hf_lo);
        embed_frag<<<NSTEP, 256, 0, stream>>>(prob, embed, xf_hi, xf_lo);

        void* args[] = {
            (void*)&xf_hi, (void*)&xf_lo, (void*)&hf_hi, (void*)&hf_lo,
            (void*)&cT_m, (void*)&w_ih, (void*)&w_hh, (void*)&b_ih,
            (void*)&b_hh, (void*)&w_ans, (void*)&poutm, (void*)&bar_m
        };
        err = hipLaunchCooperativeKernel((const void*)lstm_mfma,
                                         dim3(256), dim3(1024),
                                         args, DYN_LDS, stream);
        if (err == hipSuccess) {
            finalize_mfma<<<NOUT, 256, 0, stream>>>(poutm, b_ans, (float*)d_out);
            return;
        }
    }

    // ---- fallback: round-9 proven path (aliases the same ws region) ----
    float* ws     = (float*)d_ws;
    float* cT     = ws;                    // 65,536 fl
    float* pout   = ws + 65536;            // 2,031,616 fl
    float* xT     = ws + 2097152;          // 4,161,536 fl
    float* h_hist = ws + 6258688;          // 8,388,608 fl
    int*   bar    = (int*)(ws + 14647296);

    hipMemsetAsync(bar, 0, 2048, stream);
    init_state<<<256, 256, 0, stream>>>(h0, c0, h_hist, cT);
    embed_transpose<<<NSTEP, 256, 0, stream>>>(prob, embed, xT);

    void* args9[] = {
        (void*)&xT, (void*)&h_hist, (void*)&cT,
        (void*)&w_ih, (void*)&w_hh, (void*)&b_ih, (void*)&b_hh,
        (void*)&w_ans, (void*)&pout, (void*)&bar
    };
    hipLaunchCooperativeKernel((const void*)lstm_persist_hist,
                               dim3(NBLK), dim3(NTHR), args9, 0, stream);
    finalize_persist<<<NOUT, 256, 0, stream>>>(pout, b_ans, (float*)d_out);
}